// Round 6
// baseline (2264.282 us; speedup 1.0000x reference)
//
#include <hip/hip_runtime.h>

#define DH 128
#define NLAYER 3
typedef unsigned short ushort_t;
typedef __attribute__((ext_vector_type(8))) short bf16x8;
typedef __attribute__((ext_vector_type(4))) float f32x4;

// ---- bf16 split helpers (RNE) ----
__device__ __forceinline__ ushort_t f2bf(float a) {
    unsigned u = __float_as_uint(a);
    return (ushort_t)((u + 0x7fffu + ((u >> 16) & 1u)) >> 16);
}
__device__ __forceinline__ float bf2f(ushort_t h) {
    return __uint_as_float(((unsigned)h) << 16);
}

// ---- sortable-uint encoding for float atomic max ----
__device__ __forceinline__ unsigned enc_f(float f) {
    unsigned u = __float_as_uint(f);
    return (u & 0x80000000u) ? ~u : (u | 0x80000000u);
}
__device__ __forceinline__ float dec_f(unsigned u) {
    unsigned b = (u & 0x80000000u) ? (u ^ 0x80000000u) : ~u;
    return __uint_as_float(b);
}
#define ENC_NEG_INF 0x007FFFFFu

__global__ void fill_u(unsigned* __restrict__ p, int n, unsigned v) {
    int i = blockIdx.x * blockDim.x + threadIdx.x;
    int stride = gridDim.x * blockDim.x;
    for (; i < n; i += stride) p[i] = v;
}

__global__ void hist_kernel(const int* __restrict__ dst, unsigned* __restrict__ cnt, int E) {
    int e = blockIdx.x * blockDim.x + threadIdx.x;
    int stride = gridDim.x * blockDim.x;
    for (; e < E; e += stride) atomicAdd(&cnt[dst[e]], 1u);
}

// ---- multi-block scan: local scan -> base scan -> add+zero ----
__global__ __launch_bounds__(1024) void scan_local(const unsigned* __restrict__ cnt,
                                                   unsigned* __restrict__ off,
                                                   unsigned* __restrict__ bsum, int n) {
    __shared__ unsigned s[1024];
    const int t = threadIdx.x;
    int idx = blockIdx.x * 1024 + t;
    unsigned v = (idx < n) ? cnt[idx] : 0u;
    s[t] = v;
    __syncthreads();
    for (int d = 1; d < 1024; d <<= 1) {
        unsigned u = (t >= d) ? s[t - d] : 0u;
        __syncthreads();
        s[t] += u;
        __syncthreads();
    }
    if (idx < n) off[idx] = s[t] - v;          // exclusive within block
    if (t == 1023) bsum[blockIdx.x] = s[t];
}
__global__ void scan_base(unsigned* __restrict__ bsum, int nb) {
    __shared__ unsigned s[64];
    const int t = threadIdx.x;
    unsigned v = (t < nb) ? bsum[t] : 0u;
    s[t] = v;
    __syncthreads();
    for (int d = 1; d < 64; d <<= 1) {
        unsigned u = (t >= d) ? s[t - d] : 0u;
        __syncthreads();
        s[t] += u;
        __syncthreads();
    }
    if (t < nb) bsum[t] = s[t] - v;            // exclusive
}
__global__ void scan_add(unsigned* __restrict__ off, const unsigned* __restrict__ bsum,
                         unsigned* __restrict__ cnt, int n) {
    int i = blockIdx.x * blockDim.x + threadIdx.x;
    int stride = gridDim.x * blockDim.x;
    for (; i < n; i += stride) { off[i] += bsum[i >> 10]; cnt[i] = 0u; }
}

__global__ void scatter_kernel(const int* __restrict__ src, const int* __restrict__ dst,
                               const unsigned* __restrict__ off, unsigned* __restrict__ cur,
                               int* __restrict__ s_src, int* __restrict__ s_dst, int E) {
    int e = blockIdx.x * blockDim.x + threadIdx.x;
    int stride = gridDim.x * blockDim.x;
    for (; e < E; e += stride) {
        int d = dst[e];
        unsigned p = off[d] + atomicAdd(&cur[d], 1u);
        s_src[p] = src[e];
        s_dst[p] = d;
    }
}

// W1t[l][c'][k]: c'<128 -> A-cols (W1[l][k][c']), c'>=128 -> B-cols (W1[l][128+k][c'-128])
// W2t[l][c][k] = W2[l][k][c]. All split into hi/lo bf16.
__global__ void convert_w(const float* __restrict__ W1, const float* __restrict__ W2,
                          ushort_t* __restrict__ W1t_hi, ushort_t* __restrict__ W1t_lo,
                          ushort_t* __restrict__ W2t_hi, ushort_t* __restrict__ W2t_lo) {
    const int T1 = NLAYER * 256 * DH, T2 = NLAYER * DH * DH;
    int i = blockIdx.x * blockDim.x + threadIdx.x;
    int stride = gridDim.x * blockDim.x;
    for (; i < T1 + T2; i += stride) {
        if (i < T1) {
            int l = i >> 15, r = i & 32767, c = r >> 7, k = r & 127;
            float w = W1[(size_t)l * 32768 + (size_t)((c < 128) ? k : 128 + k) * DH + (c & 127)];
            ushort_t hi = f2bf(w);
            W1t_hi[i] = hi; W1t_lo[i] = f2bf(w - bf2f(hi));
        } else {
            int j = i - T1;
            int l = j >> 14, r = j & 16383, c = r >> 7, k = r & 127;
            float w = W2[(size_t)l * 16384 + (size_t)k * DH + c];
            ushort_t hi = f2bf(w);
            W2t_hi[j] = hi; W2t_lo[j] = f2bf(w - bf2f(hi));
        }
    }
}

// z -> packed (hi | lo<<16) per element, into hpk
__global__ void convert_h(const float* __restrict__ z, unsigned* __restrict__ hpk, int n) {
    int i = blockIdx.x * blockDim.x + threadIdx.x;
    int stride = gridDim.x * blockDim.x;
    for (; i < n; i += stride) {
        float a = z[i];
        ushort_t hi = f2bf(a);
        ushort_t lo = f2bf(a - bf2f(hi));
        hpk[i] = (unsigned)hi | ((unsigned)lo << 16);
    }
}

// C[row, col] = sum_k h[row][k] * Wt[col][k] via split-bf16 MFMA.
// 512 thr, 256 rows x 128 cols/block, 8 waves (32 rows each).
// rt processed SEQUENTIALLY to keep live frags at 32 regs -> 2 blocks/CU.
__global__ __launch_bounds__(512, 4) void node_gemm(
    const unsigned* __restrict__ hpk,
    const ushort_t* __restrict__ wthi, const ushort_t* __restrict__ wtlo,
    const float* __restrict__ bias, float* __restrict__ outp, int N) {
    __shared__ char smem[65536];
    char* Whi = smem;
    char* Wlo = smem + 32768;
    const int t = threadIdx.x;
    const int w = t >> 6, l = t & 63;
    for (int cid = t; cid < 2048; cid += 512) {
        int c = cid >> 4, ch = cid & 15;
        uint4 vh = *(const uint4*)(wthi + (size_t)cid * 8);
        uint4 vl = *(const uint4*)(wtlo + (size_t)cid * 8);
        *(uint4*)(Whi + c * 256 + ((ch ^ (c & 15)) << 4)) = vh;
        *(uint4*)(Wlo + c * 256 + ((ch ^ (c & 15)) << 4)) = vl;
    }
    const int n0 = blockIdx.x * 256;
    f32x4 acc[2][8];
    #pragma unroll
    for (int rt = 0; rt < 2; ++rt)
        #pragma unroll
        for (int ct = 0; ct < 8; ++ct) acc[rt][ct] = (f32x4){0.f, 0.f, 0.f, 0.f};
    __syncthreads();
    #pragma unroll
    for (int rt = 0; rt < 2; ++rt) {
        bf16x8 ahi[4], alo[4];
        int row = n0 + w * 32 + rt * 16 + (l & 15);
        if (row >= N) row = N - 1;
        const unsigned* ph = hpk + (size_t)row * DH + 8 * (l >> 4);
        #pragma unroll
        for (int ks = 0; ks < 4; ++ks) {
            uint4 p0 = *(const uint4*)(ph + ks * 32);
            uint4 p1 = *(const uint4*)(ph + ks * 32 + 4);
            bf16x8 hv, lv;
            hv[0] = (short)(p0.x & 0xffffu); lv[0] = (short)(p0.x >> 16);
            hv[1] = (short)(p0.y & 0xffffu); lv[1] = (short)(p0.y >> 16);
            hv[2] = (short)(p0.z & 0xffffu); lv[2] = (short)(p0.z >> 16);
            hv[3] = (short)(p0.w & 0xffffu); lv[3] = (short)(p0.w >> 16);
            hv[4] = (short)(p1.x & 0xffffu); lv[4] = (short)(p1.x >> 16);
            hv[5] = (short)(p1.y & 0xffffu); lv[5] = (short)(p1.y >> 16);
            hv[6] = (short)(p1.z & 0xffffu); lv[6] = (short)(p1.z >> 16);
            hv[7] = (short)(p1.w & 0xffffu); lv[7] = (short)(p1.w >> 16);
            ahi[ks] = hv; alo[ks] = lv;
        }
        #pragma unroll
        for (int ct = 0; ct < 8; ++ct) {
            int colv = ct * 16 + (l & 15);
            #pragma unroll
            for (int ks = 0; ks < 4; ++ks) {
                int chb = ks * 4 + (l >> 4);
                int addr = colv * 256 + ((chb ^ (colv & 15)) << 4);
                bf16x8 bh = *(const bf16x8*)(Whi + addr);
                bf16x8 bl = *(const bf16x8*)(Wlo + addr);
                acc[rt][ct] = __builtin_amdgcn_mfma_f32_16x16x32_bf16(ahi[ks], bh, acc[rt][ct], 0, 0, 0);
                acc[rt][ct] = __builtin_amdgcn_mfma_f32_16x16x32_bf16(ahi[ks], bl, acc[rt][ct], 0, 0, 0);
                acc[rt][ct] = __builtin_amdgcn_mfma_f32_16x16x32_bf16(alo[ks], bh, acc[rt][ct], 0, 0, 0);
            }
        }
    }
    #pragma unroll
    for (int ct = 0; ct < 8; ++ct) {
        int col = ct * 16 + (l & 15);
        float bv = bias ? bias[col] : 0.0f;
        #pragma unroll
        for (int rt = 0; rt < 2; ++rt)
            #pragma unroll
            for (int i = 0; i < 4; ++i) {
                int row = n0 + w * 32 + rt * 16 + (l >> 4) * 4 + i;
                if (row < N) outp[(size_t)row * DH + col] = acc[rt][ct][i] + bv;
            }
    }
}

// Edge kernel: 256 sorted edges x 128 cols per block, 8 waves; rt sequential.
__global__ __launch_bounds__(512, 4) void edge_mlp(
    const float* __restrict__ Afp, const float* __restrict__ Bfp,
    const int* __restrict__ src, const int* __restrict__ dst,
    const ushort_t* __restrict__ w2hi, const ushort_t* __restrict__ w2lo,
    unsigned* __restrict__ agg, int E) {
    __shared__ char smem[67584];
    char* Whi = smem;
    char* Wlo = smem + 32768;
    int* sdst = (int*)(smem + 65536);
    int* ssrc = sdst + 256;
    float (*R)[64] = (float (*)[64])smem;   // overlays Whi after MFMA phase
    const int t = threadIdx.x;
    const int w = t >> 6, l = t & 63;
    const int e0 = blockIdx.x * 256;
    if (t < 256) { sdst[t] = dst[e0 + t]; ssrc[t] = src[e0 + t]; }
    for (int cid = t; cid < 2048; cid += 512) {
        int c = cid >> 4, ch = cid & 15;
        uint4 vh = *(const uint4*)(w2hi + (size_t)cid * 8);
        uint4 vl = *(const uint4*)(w2lo + (size_t)cid * 8);
        *(uint4*)(Whi + c * 256 + ((ch ^ (c & 15)) << 4)) = vh;
        *(uint4*)(Wlo + c * 256 + ((ch ^ (c & 15)) << 4)) = vl;
    }
    f32x4 acc[2][8];
    #pragma unroll
    for (int rt = 0; rt < 2; ++rt)
        #pragma unroll
        for (int ct = 0; ct < 8; ++ct) acc[rt][ct] = (f32x4){0.f, 0.f, 0.f, 0.f};
    __syncthreads();
    #pragma unroll
    for (int rt = 0; rt < 2; ++rt) {
        // gather + relu + bf16-split into this rt's A-fragments (32 regs live)
        bf16x8 ahi[4], alo[4];
        int er = w * 32 + rt * 16 + (l & 15);
        int dn = sdst[er], sn = ssrc[er];
        const float* pa = Afp + (size_t)dn * DH + 8 * (l >> 4);
        const float* pb = Bfp + (size_t)sn * DH + 8 * (l >> 4);
        #pragma unroll
        for (int ks = 0; ks < 4; ++ks) {
            float4 a0 = *(const float4*)(pa + ks * 32);
            float4 a1 = *(const float4*)(pa + ks * 32 + 4);
            float4 b0 = *(const float4*)(pb + ks * 32);
            float4 b1 = *(const float4*)(pb + ks * 32 + 4);
            float v0 = fmaxf(a0.x + b0.x, 0.f), v1 = fmaxf(a0.y + b0.y, 0.f);
            float v2 = fmaxf(a0.z + b0.z, 0.f), v3 = fmaxf(a0.w + b0.w, 0.f);
            float v4 = fmaxf(a1.x + b1.x, 0.f), v5 = fmaxf(a1.y + b1.y, 0.f);
            float v6 = fmaxf(a1.z + b1.z, 0.f), v7 = fmaxf(a1.w + b1.w, 0.f);
            ushort_t h0 = f2bf(v0), h1 = f2bf(v1), h2 = f2bf(v2), h3 = f2bf(v3);
            ushort_t h4 = f2bf(v4), h5 = f2bf(v5), h6 = f2bf(v6), h7 = f2bf(v7);
            bf16x8 hv, lv;
            hv[0] = (short)h0; lv[0] = (short)f2bf(v0 - bf2f(h0));
            hv[1] = (short)h1; lv[1] = (short)f2bf(v1 - bf2f(h1));
            hv[2] = (short)h2; lv[2] = (short)f2bf(v2 - bf2f(h2));
            hv[3] = (short)h3; lv[3] = (short)f2bf(v3 - bf2f(h3));
            hv[4] = (short)h4; lv[4] = (short)f2bf(v4 - bf2f(h4));
            hv[5] = (short)h5; lv[5] = (short)f2bf(v5 - bf2f(h5));
            hv[6] = (short)h6; lv[6] = (short)f2bf(v6 - bf2f(h6));
            hv[7] = (short)h7; lv[7] = (short)f2bf(v7 - bf2f(h7));
            ahi[ks] = hv; alo[ks] = lv;
        }
        #pragma unroll
        for (int ct = 0; ct < 8; ++ct) {
            int colv = ct * 16 + (l & 15);
            #pragma unroll
            for (int ks = 0; ks < 4; ++ks) {
                int chb = ks * 4 + (l >> 4);
                int addr = colv * 256 + ((chb ^ (colv & 15)) << 4);
                bf16x8 bh = *(const bf16x8*)(Whi + addr);
                bf16x8 bl = *(const bf16x8*)(Wlo + addr);
                acc[rt][ct] = __builtin_amdgcn_mfma_f32_16x16x32_bf16(ahi[ks], bh, acc[rt][ct], 0, 0, 0);
                acc[rt][ct] = __builtin_amdgcn_mfma_f32_16x16x32_bf16(ahi[ks], bl, acc[rt][ct], 0, 0, 0);
                acc[rt][ct] = __builtin_amdgcn_mfma_f32_16x16x32_bf16(alo[ks], bh, acc[rt][ct], 0, 0, 0);
            }
        }
    }
    // segmented max over sorted dst runs; stage 128 rows x 64 cols at a time in R
    #pragma unroll
    for (int eh = 0; eh < 2; ++eh) {
        #pragma unroll
        for (int chh = 0; chh < 2; ++chh) {
            __syncthreads();
            if ((w >> 2) == eh) {
                #pragma unroll
                for (int rt = 0; rt < 2; ++rt)
                    #pragma unroll
                    for (int c4 = 0; c4 < 4; ++c4) {
                        int ct = chh * 4 + c4;
                        int col64 = c4 * 16 + (l & 15);
                        #pragma unroll
                        for (int i = 0; i < 4; ++i) {
                            int row = (w & 3) * 32 + rt * 16 + (l >> 4) * 4 + i;
                            R[row][col64 ^ (((row >> 2) & 3) << 4)] = acc[rt][ct][i];
                        }
                    }
            }
            __syncthreads();
            int col = t & 63;
            int r0 = (t >> 6) * 16;
            float run = R[r0][col ^ (((r0 >> 2) & 3) << 4)];
            int cur = sdst[eh * 128 + r0];
            #pragma unroll
            for (int rr = r0 + 1; rr < r0 + 16; ++rr) {
                float x = R[rr][col ^ (((rr >> 2) & 3) << 4)];
                int dd = sdst[eh * 128 + rr];
                if (dd != cur) {
                    atomicMax(&agg[(size_t)cur * DH + chh * 64 + col], enc_f(run));
                    cur = dd; run = x;
                } else {
                    run = fmaxf(run, x);
                }
            }
            atomicMax(&agg[(size_t)cur * DH + chh * 64 + col], enc_f(run));
        }
    }
}

// mode 0: h = relu(agg+b2) -> packed (hi|lo) in place; mode 1: out = agg+b2 fp32
__global__ void finalize_kernel(unsigned* agg, const float* __restrict__ b2,
                                unsigned* hpk, float* __restrict__ outf, int n, int mode) {
    int i = blockIdx.x * blockDim.x + threadIdx.x;
    int stride = gridDim.x * blockDim.x;
    for (; i < n; i += stride) {
        unsigned uv = agg[i];
        float f = (uv == ENC_NEG_INF) ? 0.0f : dec_f(uv) + b2[i & (DH - 1)];
        if (mode == 0) {
            f = fmaxf(f, 0.0f);
            ushort_t hi = f2bf(f);
            ushort_t lo = f2bf(f - bf2f(hi));
            hpk[i] = (unsigned)hi | ((unsigned)lo << 16);
        } else {
            outf[i] = f;
        }
    }
}

extern "C" void kernel_launch(void* const* d_in, const int* in_sizes, int n_in,
                              void* d_out, int out_size, void* d_ws, size_t ws_size,
                              hipStream_t stream) {
    const float* z  = (const float*)d_in[0];
    const int*   ei = (const int*)d_in[1];
    const float* W1 = (const float*)d_in[2];
    const float* b1 = (const float*)d_in[3];
    const float* W2 = (const float*)d_in[4];
    const float* b2 = (const float*)d_in[5];
    const int N = 50000, D = DH, E = 800000;
    const int* srcp = ei;
    const int* dstp = ei + E;

    float* Abuf = (float*)d_ws;
    float* Bbuf = Abuf + (size_t)N * D;
    unsigned* agg = (unsigned*)(Bbuf + (size_t)N * D);
    ushort_t* W1t_hi = (ushort_t*)(agg + (size_t)N * D);
    ushort_t* W1t_lo = W1t_hi + NLAYER * 256 * D;
    ushort_t* W2t_hi = W1t_lo + NLAYER * 256 * D;
    ushort_t* W2t_lo = W2t_hi + NLAYER * D * D;
    unsigned* cnt = (unsigned*)(W2t_lo + NLAYER * D * D);
    unsigned* off = cnt + N;
    unsigned* bsum = off + N;
    int* s_src = (int*)(bsum + 64);
    int* s_dst = s_src + E;
    float* outp = (float*)d_out;

    convert_w<<<128, 256, 0, stream>>>(W1, W2, W1t_hi, W1t_lo, W2t_hi, W2t_lo);
    convert_h<<<1024, 256, 0, stream>>>(z, agg, N * D);   // packed h lives in agg buffer

    const int NB = (N + 1023) / 1024;   // 49
    fill_u<<<256, 256, 0, stream>>>(cnt, N, 0u);
    hist_kernel<<<1024, 256, 0, stream>>>(dstp, cnt, E);
    scan_local<<<NB, 1024, 0, stream>>>(cnt, off, bsum, N);
    scan_base<<<1, 64, 0, stream>>>(bsum, NB);
    scan_add<<<256, 256, 0, stream>>>(off, bsum, cnt, N);
    scatter_kernel<<<1024, 256, 0, stream>>>(srcp, dstp, off, cnt, s_src, s_dst, E);

    const int nrb = (N + 255) / 256;
    for (int l = 0; l < NLAYER; ++l) {
        node_gemm<<<nrb, 512, 0, stream>>>(agg, W1t_hi + ((size_t)l * 256) * D,
                                           W1t_lo + ((size_t)l * 256) * D,
                                           b1 + (size_t)l * D, Abuf, N);
        node_gemm<<<nrb, 512, 0, stream>>>(agg, W1t_hi + ((size_t)l * 256 + 128) * D,
                                           W1t_lo + ((size_t)l * 256 + 128) * D,
                                           nullptr, Bbuf, N);
        fill_u<<<2048, 256, 0, stream>>>(agg, N * D, ENC_NEG_INF);
        edge_mlp<<<E / 256, 512, 0, stream>>>(Abuf, Bbuf, s_src, s_dst,
                                              W2t_hi + (size_t)l * D * D,
                                              W2t_lo + (size_t)l * D * D, agg, E);
        finalize_kernel<<<2048, 256, 0, stream>>>(agg, b2 + (size_t)l * D,
                                                  agg, outp, N * D,
                                                  (l < NLAYER - 1) ? 0 : 1);
    }
}

// Round 8
// 893.875 us; speedup vs baseline: 2.5331x; 2.5331x over previous
//
#include <hip/hip_runtime.h>

#define DH 128
#define NLAYER 3
typedef unsigned short ushort_t;
typedef __attribute__((ext_vector_type(8))) short bf16x8;
typedef __attribute__((ext_vector_type(4))) float f32x4;

// ---- bf16 split helpers (RNE for hi, trunc for lo) ----
__device__ __forceinline__ ushort_t f2bf(float a) {
    unsigned u = __float_as_uint(a);
    return (ushort_t)((u + 0x7fffu + ((u >> 16) & 1u)) >> 16);
}
__device__ __forceinline__ float bf2f(ushort_t h) {
    return __uint_as_float(((unsigned)h) << 16);
}

// ---- sortable-uint encoding for float atomic max ----
__device__ __forceinline__ unsigned enc_f(float f) {
    unsigned u = __float_as_uint(f);
    return (u & 0x80000000u) ? ~u : (u | 0x80000000u);
}
__device__ __forceinline__ float dec_f(unsigned u) {
    unsigned b = (u & 0x80000000u) ? (u ^ 0x80000000u) : ~u;
    return __uint_as_float(b);
}
#define ENC_NEG_INF 0x007FFFFFu

__global__ void fill_u(unsigned* __restrict__ p, int n, unsigned v) {
    int i = blockIdx.x * blockDim.x + threadIdx.x;
    int stride = gridDim.x * blockDim.x;
    for (; i < n; i += stride) p[i] = v;
}

__global__ void hist_kernel(const int* __restrict__ dst, unsigned* __restrict__ cnt, int E) {
    int e = blockIdx.x * blockDim.x + threadIdx.x;
    int stride = gridDim.x * blockDim.x;
    for (; e < E; e += stride) atomicAdd(&cnt[dst[e]], 1u);
}

// ---- multi-block scan: local scan -> base scan -> add+zero ----
__global__ __launch_bounds__(1024) void scan_local(const unsigned* __restrict__ cnt,
                                                   unsigned* __restrict__ off,
                                                   unsigned* __restrict__ bsum, int n) {
    __shared__ unsigned s[1024];
    const int t = threadIdx.x;
    int idx = blockIdx.x * 1024 + t;
    unsigned v = (idx < n) ? cnt[idx] : 0u;
    s[t] = v;
    __syncthreads();
    for (int d = 1; d < 1024; d <<= 1) {
        unsigned u = (t >= d) ? s[t - d] : 0u;
        __syncthreads();
        s[t] += u;
        __syncthreads();
    }
    if (idx < n) off[idx] = s[t] - v;
    if (t == 1023) bsum[blockIdx.x] = s[t];
}
__global__ void scan_base(unsigned* __restrict__ bsum, int nb) {
    __shared__ unsigned s[64];
    const int t = threadIdx.x;
    unsigned v = (t < nb) ? bsum[t] : 0u;
    s[t] = v;
    __syncthreads();
    for (int d = 1; d < 64; d <<= 1) {
        unsigned u = (t >= d) ? s[t - d] : 0u;
        __syncthreads();
        s[t] += u;
        __syncthreads();
    }
    if (t < nb) bsum[t] = s[t] - v;
}
__global__ void scan_add(unsigned* __restrict__ off, const unsigned* __restrict__ bsum,
                         unsigned* __restrict__ cnt, int n) {
    int i = blockIdx.x * blockDim.x + threadIdx.x;
    int stride = gridDim.x * blockDim.x;
    for (; i < n; i += stride) { off[i] += bsum[i >> 10]; cnt[i] = 0u; }
}

__global__ void scatter_kernel(const int* __restrict__ src, const int* __restrict__ dst,
                               const unsigned* __restrict__ off, unsigned* __restrict__ cur,
                               int* __restrict__ s_src, int* __restrict__ s_dst, int E) {
    int e = blockIdx.x * blockDim.x + threadIdx.x;
    int stride = gridDim.x * blockDim.x;
    for (; e < E; e += stride) {
        int d = dst[e];
        unsigned p = off[d] + atomicAdd(&cur[d], 1u);
        s_src[p] = src[e];
        s_dst[p] = d;
    }
}

// W1t[l][c'][k]: c'<128 -> A-cols (W1[l][k][c']), c'>=128 -> B-cols (W1[l][128+k][c'-128])
// W2t[l][c][k] = W2[l][k][c]. All split into hi/lo bf16.
__global__ void convert_w(const float* __restrict__ W1, const float* __restrict__ W2,
                          ushort_t* __restrict__ W1t_hi, ushort_t* __restrict__ W1t_lo,
                          ushort_t* __restrict__ W2t_hi, ushort_t* __restrict__ W2t_lo) {
    const int T1 = NLAYER * 256 * DH, T2 = NLAYER * DH * DH;
    int i = blockIdx.x * blockDim.x + threadIdx.x;
    int stride = gridDim.x * blockDim.x;
    for (; i < T1 + T2; i += stride) {
        if (i < T1) {
            int l = i >> 15, r = i & 32767, c = r >> 7, k = r & 127;
            float w = W1[(size_t)l * 32768 + (size_t)((c < 128) ? k : 128 + k) * DH + (c & 127)];
            ushort_t hi = f2bf(w);
            W1t_hi[i] = hi; W1t_lo[i] = f2bf(w - bf2f(hi));
        } else {
            int j = i - T1;
            int l = j >> 14, r = j & 16383, c = r >> 7, k = r & 127;
            float w = W2[(size_t)l * 16384 + (size_t)k * DH + c];
            ushort_t hi = f2bf(w);
            W2t_hi[j] = hi; W2t_lo[j] = f2bf(w - bf2f(hi));
        }
    }
}

// z -> packed (hi | lo<<16) per element, into hpk
__global__ void convert_h(const float* __restrict__ z, unsigned* __restrict__ hpk, int n) {
    int i = blockIdx.x * blockDim.x + threadIdx.x;
    int stride = gridDim.x * blockDim.x;
    for (; i < n; i += stride) {
        float a = z[i];
        ushort_t hi = f2bf(a);
        ushort_t lo = f2bf(a - bf2f(hi));
        hpk[i] = (unsigned)hi | ((unsigned)lo << 16);
    }
}

// C[row, col] = sum_k h[row][k] * Wt[col][k] via split-bf16 MFMA.
// Round-4 structure: 256 thr, 128 rows x 128 cols, 4 waves, frags for both rt held.
__global__ __launch_bounds__(256, 2) void node_gemm(
    const unsigned* __restrict__ hpk,
    const ushort_t* __restrict__ wthi, const ushort_t* __restrict__ wtlo,
    const float* __restrict__ bias, float* __restrict__ outp, int N) {
    __shared__ char smem[65536];
    char* Whi = smem;
    char* Wlo = smem + 32768;
    const int t = threadIdx.x;
    const int w = t >> 6, l = t & 63;
    for (int cid = t; cid < 2048; cid += 256) {
        int c = cid >> 4, ch = cid & 15;
        uint4 vh = *(const uint4*)(wthi + (size_t)cid * 8);
        uint4 vl = *(const uint4*)(wtlo + (size_t)cid * 8);
        *(uint4*)(Whi + c * 256 + ((ch ^ (c & 15)) << 4)) = vh;
        *(uint4*)(Wlo + c * 256 + ((ch ^ (c & 15)) << 4)) = vl;
    }
    const int n0 = blockIdx.x * 128;
    bf16x8 ahi[2][4], alo[2][4];
    #pragma unroll
    for (int rt = 0; rt < 2; ++rt) {
        int row = n0 + w * 32 + rt * 16 + (l & 15);
        if (row >= N) row = N - 1;
        const unsigned* ph = hpk + (size_t)row * DH + 8 * (l >> 4);
        #pragma unroll
        for (int ks = 0; ks < 4; ++ks) {
            uint4 p0 = *(const uint4*)(ph + ks * 32);
            uint4 p1 = *(const uint4*)(ph + ks * 32 + 4);
            bf16x8 hv, lv;
            hv[0] = (short)(p0.x & 0xffffu); lv[0] = (short)(p0.x >> 16);
            hv[1] = (short)(p0.y & 0xffffu); lv[1] = (short)(p0.y >> 16);
            hv[2] = (short)(p0.z & 0xffffu); lv[2] = (short)(p0.z >> 16);
            hv[3] = (short)(p0.w & 0xffffu); lv[3] = (short)(p0.w >> 16);
            hv[4] = (short)(p1.x & 0xffffu); lv[4] = (short)(p1.x >> 16);
            hv[5] = (short)(p1.y & 0xffffu); lv[5] = (short)(p1.y >> 16);
            hv[6] = (short)(p1.z & 0xffffu); lv[6] = (short)(p1.z >> 16);
            hv[7] = (short)(p1.w & 0xffffu); lv[7] = (short)(p1.w >> 16);
            ahi[rt][ks] = hv; alo[rt][ks] = lv;
        }
    }
    f32x4 acc[2][8];
    #pragma unroll
    for (int rt = 0; rt < 2; ++rt)
        #pragma unroll
        for (int ct = 0; ct < 8; ++ct) acc[rt][ct] = (f32x4){0.f, 0.f, 0.f, 0.f};
    __syncthreads();
    #pragma unroll
    for (int ct = 0; ct < 8; ++ct) {
        int colv = ct * 16 + (l & 15);
        #pragma unroll
        for (int ks = 0; ks < 4; ++ks) {
            int chb = ks * 4 + (l >> 4);
            int addr = colv * 256 + ((chb ^ (colv & 15)) << 4);
            bf16x8 bh = *(const bf16x8*)(Whi + addr);
            bf16x8 bl = *(const bf16x8*)(Wlo + addr);
            #pragma unroll
            for (int rt = 0; rt < 2; ++rt) {
                acc[rt][ct] = __builtin_amdgcn_mfma_f32_16x16x32_bf16(ahi[rt][ks], bh, acc[rt][ct], 0, 0, 0);
                acc[rt][ct] = __builtin_amdgcn_mfma_f32_16x16x32_bf16(ahi[rt][ks], bl, acc[rt][ct], 0, 0, 0);
                acc[rt][ct] = __builtin_amdgcn_mfma_f32_16x16x32_bf16(alo[rt][ks], bh, acc[rt][ct], 0, 0, 0);
            }
        }
    }
    #pragma unroll
    for (int ct = 0; ct < 8; ++ct) {
        int col = ct * 16 + (l & 15);
        float bv = bias ? bias[col] : 0.0f;
        #pragma unroll
        for (int rt = 0; rt < 2; ++rt)
            #pragma unroll
            for (int i = 0; i < 4; ++i) {
                int row = n0 + w * 32 + rt * 16 + (l >> 4) * 4 + i;
                if (row < N) outp[(size_t)row * DH + col] = acc[rt][ct][i] + bv;
            }
    }
}

// Edge kernel v6: 128 sorted edges x 128 cols per block, 4 waves, 256 thr.
// Two independent blocks co-resident per CU (LDS 66KB, regs ~150) -> de-synced overlap.
// dn/sn read directly from global (no pre-gather barrier). Epilogue: 2 phases.
__global__ __launch_bounds__(256, 2) void edge_mlp(
    const float* __restrict__ Afp, const float* __restrict__ Bfp,
    const int* __restrict__ src, const int* __restrict__ dst,
    const ushort_t* __restrict__ w2hi, const ushort_t* __restrict__ w2lo,
    unsigned* __restrict__ agg, int E) {
    __shared__ char smem[66048];           // Whi 32K | Wlo 32K | sdst 512B
    char* Whi = smem;
    char* Wlo = smem + 32768;
    int* sdst = (int*)(smem + 65536);
    float* R = (float*)smem;               // 128 x 64 f32 overlays Whi after MFMA
    const int t = threadIdx.x;
    const int w = t >> 6, l = t & 63;
    const int e0 = blockIdx.x * 128;

    // gather + relu + bf16-split into A-fragments (indices straight from global)
    bf16x8 ahi[2][4], alo[2][4];
    #pragma unroll
    for (int rt = 0; rt < 2; ++rt) {
        int er = w * 32 + rt * 16 + (l & 15);
        int dn = dst[e0 + er], sn = src[e0 + er];   // 16-lane broadcast loads
        const float* pa = Afp + (size_t)dn * DH + 8 * (l >> 4);
        const float* pb = Bfp + (size_t)sn * DH + 8 * (l >> 4);
        #pragma unroll
        for (int ks = 0; ks < 4; ++ks) {
            float4 a0 = *(const float4*)(pa + ks * 32);
            float4 a1 = *(const float4*)(pa + ks * 32 + 4);
            float4 b0 = *(const float4*)(pb + ks * 32);
            float4 b1 = *(const float4*)(pb + ks * 32 + 4);
            float v0 = fmaxf(a0.x + b0.x, 0.f), v1 = fmaxf(a0.y + b0.y, 0.f);
            float v2 = fmaxf(a0.z + b0.z, 0.f), v3 = fmaxf(a0.w + b0.w, 0.f);
            float v4 = fmaxf(a1.x + b1.x, 0.f), v5 = fmaxf(a1.y + b1.y, 0.f);
            float v6 = fmaxf(a1.z + b1.z, 0.f), v7 = fmaxf(a1.w + b1.w, 0.f);
            ushort_t h0 = f2bf(v0), h1 = f2bf(v1), h2 = f2bf(v2), h3 = f2bf(v3);
            ushort_t h4 = f2bf(v4), h5 = f2bf(v5), h6 = f2bf(v6), h7 = f2bf(v7);
            bf16x8 hv, lv;
            hv[0] = (short)h0; lv[0] = (short)f2bf(v0 - bf2f(h0));
            hv[1] = (short)h1; lv[1] = (short)f2bf(v1 - bf2f(h1));
            hv[2] = (short)h2; lv[2] = (short)f2bf(v2 - bf2f(h2));
            hv[3] = (short)h3; lv[3] = (short)f2bf(v3 - bf2f(h3));
            hv[4] = (short)h4; lv[4] = (short)f2bf(v4 - bf2f(h4));
            hv[5] = (short)h5; lv[5] = (short)f2bf(v5 - bf2f(h5));
            hv[6] = (short)h6; lv[6] = (short)f2bf(v6 - bf2f(h6));
            hv[7] = (short)h7; lv[7] = (short)f2bf(v7 - bf2f(h7));
            ahi[rt][ks] = hv; alo[rt][ks] = lv;
        }
    }
    // stage W (hi/lo, 16B-chunk XOR swizzle) + sdst
    if (t < 128) sdst[t] = dst[e0 + t];
    for (int cid = t; cid < 2048; cid += 256) {
        int c = cid >> 4, ch = cid & 15;
        uint4 vh = *(const uint4*)(w2hi + (size_t)cid * 8);
        uint4 vl = *(const uint4*)(w2lo + (size_t)cid * 8);
        *(uint4*)(Whi + c * 256 + ((ch ^ (c & 15)) << 4)) = vh;
        *(uint4*)(Wlo + c * 256 + ((ch ^ (c & 15)) << 4)) = vl;
    }
    f32x4 acc[2][8];
    #pragma unroll
    for (int rt = 0; rt < 2; ++rt)
        #pragma unroll
        for (int ct = 0; ct < 8; ++ct) acc[rt][ct] = (f32x4){0.f, 0.f, 0.f, 0.f};
    __syncthreads();
    #pragma unroll
    for (int ct = 0; ct < 8; ++ct) {
        int colv = ct * 16 + (l & 15);
        #pragma unroll
        for (int ks = 0; ks < 4; ++ks) {
            int chb = ks * 4 + (l >> 4);
            int addr = colv * 256 + ((chb ^ (colv & 15)) << 4);
            bf16x8 bh = *(const bf16x8*)(Whi + addr);
            bf16x8 bl = *(const bf16x8*)(Wlo + addr);
            #pragma unroll
            for (int rt = 0; rt < 2; ++rt) {
                acc[rt][ct] = __builtin_amdgcn_mfma_f32_16x16x32_bf16(ahi[rt][ks], bh, acc[rt][ct], 0, 0, 0);
                acc[rt][ct] = __builtin_amdgcn_mfma_f32_16x16x32_bf16(ahi[rt][ks], bl, acc[rt][ct], 0, 0, 0);
                acc[rt][ct] = __builtin_amdgcn_mfma_f32_16x16x32_bf16(alo[rt][ks], bh, acc[rt][ct], 0, 0, 0);
            }
        }
    }
    // segmented max: 2 phases (64 cols each); R = 128x64 f32 overlays Whi
    #pragma unroll
    for (int chh = 0; chh < 2; ++chh) {
        __syncthreads();
        #pragma unroll
        for (int rt = 0; rt < 2; ++rt)
            #pragma unroll
            for (int c4 = 0; c4 < 4; ++c4) {
                int ct = chh * 4 + c4;
                int col64 = c4 * 16 + (l & 15);
                #pragma unroll
                for (int i = 0; i < 4; ++i) {
                    int row = w * 32 + rt * 16 + (l >> 4) * 4 + i;
                    R[row * 64 + (col64 ^ (((row >> 2) & 3) << 4))] = acc[rt][ct][i];
                }
            }
        __syncthreads();
        const int col = l;            // 64 cols per wave's lanes
        const int r0 = w * 32;
        float run = R[r0 * 64 + (col ^ (((r0 >> 2) & 3) << 4))];
        int cur = sdst[r0];
        #pragma unroll
        for (int rr = r0 + 1; rr < r0 + 32; ++rr) {
            float x = R[rr * 64 + (col ^ (((rr >> 2) & 3) << 4))];
            int dd = sdst[rr];
            if (dd != cur) {
                atomicMax(&agg[(size_t)cur * DH + chh * 64 + col], enc_f(run));
                cur = dd; run = x;
            } else {
                run = fmaxf(run, x);
            }
        }
        atomicMax(&agg[(size_t)cur * DH + chh * 64 + col], enc_f(run));
    }
}

// mode 0: h = relu(agg+b2) -> packed (hi|lo) in place; mode 1: out = agg+b2 fp32
__global__ void finalize_kernel(unsigned* agg, const float* __restrict__ b2,
                                unsigned* hpk, float* __restrict__ outf, int n, int mode) {
    int i = blockIdx.x * blockDim.x + threadIdx.x;
    int stride = gridDim.x * blockDim.x;
    for (; i < n; i += stride) {
        unsigned uv = agg[i];
        float f = (uv == ENC_NEG_INF) ? 0.0f : dec_f(uv) + b2[i & (DH - 1)];
        if (mode == 0) {
            f = fmaxf(f, 0.0f);
            ushort_t hi = f2bf(f);
            ushort_t lo = f2bf(f - bf2f(hi));
            hpk[i] = (unsigned)hi | ((unsigned)lo << 16);
        } else {
            outf[i] = f;
        }
    }
}

extern "C" void kernel_launch(void* const* d_in, const int* in_sizes, int n_in,
                              void* d_out, int out_size, void* d_ws, size_t ws_size,
                              hipStream_t stream) {
    const float* z  = (const float*)d_in[0];
    const int*   ei = (const int*)d_in[1];
    const float* W1 = (const float*)d_in[2];
    const float* b1 = (const float*)d_in[3];
    const float* W2 = (const float*)d_in[4];
    const float* b2 = (const float*)d_in[5];
    const int N = 50000, D = DH, E = 800000;
    const int* srcp = ei;
    const int* dstp = ei + E;

    float* Abuf = (float*)d_ws;
    float* Bbuf = Abuf + (size_t)N * D;
    unsigned* agg = (unsigned*)(Bbuf + (size_t)N * D);
    ushort_t* W1t_hi = (ushort_t*)(agg + (size_t)N * D);
    ushort_t* W1t_lo = W1t_hi + NLAYER * 256 * D;
    ushort_t* W2t_hi = W1t_lo + NLAYER * 256 * D;
    ushort_t* W2t_lo = W2t_hi + NLAYER * D * D;
    unsigned* cnt = (unsigned*)(W2t_lo + NLAYER * D * D);
    unsigned* off = cnt + N;
    unsigned* bsum = off + N;
    int* s_src = (int*)(bsum + 64);
    int* s_dst = s_src + E;
    float* outp = (float*)d_out;

    convert_w<<<128, 256, 0, stream>>>(W1, W2, W1t_hi, W1t_lo, W2t_hi, W2t_lo);
    convert_h<<<1024, 256, 0, stream>>>(z, agg, N * D);   // packed h lives in agg buffer

    const int NB = (N + 1023) / 1024;   // 49
    fill_u<<<256, 256, 0, stream>>>(cnt, N, 0u);
    hist_kernel<<<1024, 256, 0, stream>>>(dstp, cnt, E);
    scan_local<<<NB, 1024, 0, stream>>>(cnt, off, bsum, N);
    scan_base<<<1, 64, 0, stream>>>(bsum, NB);
    scan_add<<<256, 256, 0, stream>>>(off, bsum, cnt, N);
    scatter_kernel<<<1024, 256, 0, stream>>>(srcp, dstp, off, cnt, s_src, s_dst, E);

    const int nrb = (N + 127) / 128;
    for (int l = 0; l < NLAYER; ++l) {
        node_gemm<<<nrb, 256, 0, stream>>>(agg, W1t_hi + ((size_t)l * 256) * D,
                                           W1t_lo + ((size_t)l * 256) * D,
                                           b1 + (size_t)l * D, Abuf, N);
        node_gemm<<<nrb, 256, 0, stream>>>(agg, W1t_hi + ((size_t)l * 256 + 128) * D,
                                           W1t_lo + ((size_t)l * 256 + 128) * D,
                                           nullptr, Bbuf, N);
        fill_u<<<2048, 256, 0, stream>>>(agg, N * D, ENC_NEG_INF);
        edge_mlp<<<E / 128, 256, 0, stream>>>(Abuf, Bbuf, s_src, s_dst,
                                              W2t_hi + (size_t)l * D * D,
                                              W2t_lo + (size_t)l * D * D, agg, E);
        finalize_kernel<<<2048, 256, 0, stream>>>(agg, b2 + (size_t)l * D,
                                                  agg, outp, N * D,
                                                  (l < NLAYER - 1) ? 0 : 1);
    }
}

// Round 9
// 782.300 us; speedup vs baseline: 2.8944x; 1.1426x over previous
//
#include <hip/hip_runtime.h>

#define DH 128
#define NLAYER 3
typedef unsigned short ushort_t;
typedef __attribute__((ext_vector_type(8))) short bf16x8;
typedef __attribute__((ext_vector_type(4))) float f32x4;

// ---- bf16 split helpers (RNE) ----
__device__ __forceinline__ ushort_t f2bf(float a) {
    unsigned u = __float_as_uint(a);
    return (ushort_t)((u + 0x7fffu + ((u >> 16) & 1u)) >> 16);
}
__device__ __forceinline__ float bf2f(ushort_t h) {
    return __uint_as_float(((unsigned)h) << 16);
}
// pack 2 f32 -> 2 bf16 in one op (lo16=cvt(a), hi16=cvt(b)); split stays exact
// because lo term is computed from the returned hi bits.
__device__ __forceinline__ unsigned cvtpk(float a, float b) {
    unsigned r;
    asm("v_cvt_pk_bf16_f32 %0, %1, %2" : "=v"(r) : "v"(a), "v"(b));
    return r;
}

// ---- sortable-uint encoding for float atomic max ----
__device__ __forceinline__ unsigned enc_f(float f) {
    unsigned u = __float_as_uint(f);
    return (u & 0x80000000u) ? ~u : (u | 0x80000000u);
}
__device__ __forceinline__ float dec_f(unsigned u) {
    unsigned b = (u & 0x80000000u) ? (u ^ 0x80000000u) : ~u;
    return __uint_as_float(b);
}
#define ENC_NEG_INF 0x007FFFFFu

__global__ void fill_u(unsigned* __restrict__ p, int n, unsigned v) {
    int i = blockIdx.x * blockDim.x + threadIdx.x;
    int stride = gridDim.x * blockDim.x;
    for (; i < n; i += stride) p[i] = v;
}

__global__ void hist_kernel(const int* __restrict__ dst, unsigned* __restrict__ cnt, int E) {
    int e = blockIdx.x * blockDim.x + threadIdx.x;
    int stride = gridDim.x * blockDim.x;
    for (; e < E; e += stride) atomicAdd(&cnt[dst[e]], 1u);
}

// ---- multi-block scan: local scan -> base scan -> add+zero ----
__global__ __launch_bounds__(1024) void scan_local(const unsigned* __restrict__ cnt,
                                                   unsigned* __restrict__ off,
                                                   unsigned* __restrict__ bsum, int n) {
    __shared__ unsigned s[1024];
    const int t = threadIdx.x;
    int idx = blockIdx.x * 1024 + t;
    unsigned v = (idx < n) ? cnt[idx] : 0u;
    s[t] = v;
    __syncthreads();
    for (int d = 1; d < 1024; d <<= 1) {
        unsigned u = (t >= d) ? s[t - d] : 0u;
        __syncthreads();
        s[t] += u;
        __syncthreads();
    }
    if (idx < n) off[idx] = s[t] - v;
    if (t == 1023) bsum[blockIdx.x] = s[t];
}
__global__ void scan_base(unsigned* __restrict__ bsum, int nb) {
    __shared__ unsigned s[64];
    const int t = threadIdx.x;
    unsigned v = (t < nb) ? bsum[t] : 0u;
    s[t] = v;
    __syncthreads();
    for (int d = 1; d < 64; d <<= 1) {
        unsigned u = (t >= d) ? s[t - d] : 0u;
        __syncthreads();
        s[t] += u;
        __syncthreads();
    }
    if (t < nb) bsum[t] = s[t] - v;
}
__global__ void scan_add(unsigned* __restrict__ off, const unsigned* __restrict__ bsum,
                         unsigned* __restrict__ cnt, int n) {
    int i = blockIdx.x * blockDim.x + threadIdx.x;
    int stride = gridDim.x * blockDim.x;
    for (; i < n; i += stride) { off[i] += bsum[i >> 10]; cnt[i] = 0u; }
}

__global__ void scatter_kernel(const int* __restrict__ src, const int* __restrict__ dst,
                               const unsigned* __restrict__ off, unsigned* __restrict__ cur,
                               int* __restrict__ s_src, int* __restrict__ s_dst, int E) {
    int e = blockIdx.x * blockDim.x + threadIdx.x;
    int stride = gridDim.x * blockDim.x;
    for (; e < E; e += stride) {
        int d = dst[e];
        unsigned p = off[d] + atomicAdd(&cur[d], 1u);
        s_src[p] = src[e];
        s_dst[p] = d;
    }
}

// W1t[l][c'][k]: c'<128 -> A-cols (W1[l][k][c']), c'>=128 -> B-cols (W1[l][128+k][c'-128])
// W2t[l][c][k] = W2[l][k][c]. All split into hi/lo bf16.
__global__ void convert_w(const float* __restrict__ W1, const float* __restrict__ W2,
                          ushort_t* __restrict__ W1t_hi, ushort_t* __restrict__ W1t_lo,
                          ushort_t* __restrict__ W2t_hi, ushort_t* __restrict__ W2t_lo) {
    const int T1 = NLAYER * 256 * DH, T2 = NLAYER * DH * DH;
    int i = blockIdx.x * blockDim.x + threadIdx.x;
    int stride = gridDim.x * blockDim.x;
    for (; i < T1 + T2; i += stride) {
        if (i < T1) {
            int l = i >> 15, r = i & 32767, c = r >> 7, k = r & 127;
            float w = W1[(size_t)l * 32768 + (size_t)((c < 128) ? k : 128 + k) * DH + (c & 127)];
            ushort_t hi = f2bf(w);
            W1t_hi[i] = hi; W1t_lo[i] = f2bf(w - bf2f(hi));
        } else {
            int j = i - T1;
            int l = j >> 14, r = j & 16383, c = r >> 7, k = r & 127;
            float w = W2[(size_t)l * 16384 + (size_t)k * DH + c];
            ushort_t hi = f2bf(w);
            W2t_hi[j] = hi; W2t_lo[j] = f2bf(w - bf2f(hi));
        }
    }
}

// z -> packed (hi | lo<<16) per element, into hpk
__global__ void convert_h(const float* __restrict__ z, unsigned* __restrict__ hpk, int n) {
    int i = blockIdx.x * blockDim.x + threadIdx.x;
    int stride = gridDim.x * blockDim.x;
    for (; i < n; i += stride) {
        float a = z[i];
        ushort_t hi = f2bf(a);
        ushort_t lo = f2bf(a - bf2f(hi));
        hpk[i] = (unsigned)hi | ((unsigned)lo << 16);
    }
}

// Fused A/B node GEMM: grid 2*nrb; blocks [0,nrb) -> A (bias), [nrb,2nrb) -> B.
// C[row, col] = sum_k h[row][k] * Wt[col][k] via split-bf16 MFMA.
__global__ __launch_bounds__(256, 2) void node_gemm(
    const unsigned* __restrict__ hpk,
    const ushort_t* __restrict__ wthi, const ushort_t* __restrict__ wtlo,
    const float* __restrict__ bias, float* __restrict__ outA, float* __restrict__ outB,
    int N, int nrb) {
    __shared__ char smem[65536];
    char* Whi = smem;
    char* Wlo = smem + 32768;
    const int bb = blockIdx.x;
    const int half = (bb >= nrb) ? 1 : 0;
    const ushort_t* whi = wthi + (half ? (size_t)128 * DH : 0);
    const ushort_t* wlo = wtlo + (half ? (size_t)128 * DH : 0);
    float* outp = half ? outB : outA;
    const int t = threadIdx.x;
    const int w = t >> 6, l = t & 63;
    for (int cid = t; cid < 2048; cid += 256) {
        int c = cid >> 4, ch = cid & 15;
        uint4 vh = *(const uint4*)(whi + (size_t)cid * 8);
        uint4 vl = *(const uint4*)(wlo + (size_t)cid * 8);
        *(uint4*)(Whi + c * 256 + ((ch ^ (c & 15)) << 4)) = vh;
        *(uint4*)(Wlo + c * 256 + ((ch ^ (c & 15)) << 4)) = vl;
    }
    const int n0 = (bb - half * nrb) * 128;
    bf16x8 ahi[2][4], alo[2][4];
    #pragma unroll
    for (int rt = 0; rt < 2; ++rt) {
        int row = n0 + w * 32 + rt * 16 + (l & 15);
        if (row >= N) row = N - 1;
        const unsigned* ph = hpk + (size_t)row * DH + 8 * (l >> 4);
        #pragma unroll
        for (int ks = 0; ks < 4; ++ks) {
            uint4 p0 = *(const uint4*)(ph + ks * 32);
            uint4 p1 = *(const uint4*)(ph + ks * 32 + 4);
            bf16x8 hv, lv;
            hv[0] = (short)(p0.x & 0xffffu); lv[0] = (short)(p0.x >> 16);
            hv[1] = (short)(p0.y & 0xffffu); lv[1] = (short)(p0.y >> 16);
            hv[2] = (short)(p0.z & 0xffffu); lv[2] = (short)(p0.z >> 16);
            hv[3] = (short)(p0.w & 0xffffu); lv[3] = (short)(p0.w >> 16);
            hv[4] = (short)(p1.x & 0xffffu); lv[4] = (short)(p1.x >> 16);
            hv[5] = (short)(p1.y & 0xffffu); lv[5] = (short)(p1.y >> 16);
            hv[6] = (short)(p1.z & 0xffffu); lv[6] = (short)(p1.z >> 16);
            hv[7] = (short)(p1.w & 0xffffu); lv[7] = (short)(p1.w >> 16);
            ahi[rt][ks] = hv; alo[rt][ks] = lv;
        }
    }
    f32x4 acc[2][8];
    #pragma unroll
    for (int rt = 0; rt < 2; ++rt)
        #pragma unroll
        for (int ct = 0; ct < 8; ++ct) acc[rt][ct] = (f32x4){0.f, 0.f, 0.f, 0.f};
    __syncthreads();
    #pragma unroll
    for (int ct = 0; ct < 8; ++ct) {
        int colv = ct * 16 + (l & 15);
        #pragma unroll
        for (int ks = 0; ks < 4; ++ks) {
            int chb = ks * 4 + (l >> 4);
            int addr = colv * 256 + ((chb ^ (colv & 15)) << 4);
            bf16x8 bh = *(const bf16x8*)(Whi + addr);
            bf16x8 bl = *(const bf16x8*)(Wlo + addr);
            #pragma unroll
            for (int rt = 0; rt < 2; ++rt) {
                acc[rt][ct] = __builtin_amdgcn_mfma_f32_16x16x32_bf16(ahi[rt][ks], bh, acc[rt][ct], 0, 0, 0);
                acc[rt][ct] = __builtin_amdgcn_mfma_f32_16x16x32_bf16(ahi[rt][ks], bl, acc[rt][ct], 0, 0, 0);
                acc[rt][ct] = __builtin_amdgcn_mfma_f32_16x16x32_bf16(alo[rt][ks], bh, acc[rt][ct], 0, 0, 0);
            }
        }
    }
    #pragma unroll
    for (int ct = 0; ct < 8; ++ct) {
        int col = ct * 16 + (l & 15);
        float bv = half ? 0.0f : bias[col];
        #pragma unroll
        for (int rt = 0; rt < 2; ++rt)
            #pragma unroll
            for (int i = 0; i < 4; ++i) {
                int row = n0 + w * 32 + rt * 16 + (l >> 4) * 4 + i;
                if (row < N) outp[(size_t)row * DH + col] = acc[rt][ct][i] + bv;
            }
    }
}

// Edge kernel v7: 128 sorted edges x 128 cols, 4 waves, 256 thr.
// LDS cut to 33 KB by paging W2 in two 64-col halves -> 3 blocks/CU.
// hi/lo split packed via v_cvt_pk_bf16_f32 (1 op per 2 values).
__global__ __launch_bounds__(256, 2) void edge_mlp(
    const float* __restrict__ Afp, const float* __restrict__ Bfp,
    const int* __restrict__ src, const int* __restrict__ dst,
    const ushort_t* __restrict__ w2hi, const ushort_t* __restrict__ w2lo,
    unsigned* __restrict__ agg, int E) {
    __shared__ char smem[33280];     // Whi page 16K | Wlo page 16K | sdst 512B
    int* sdst = (int*)(smem + 32768);
    float* R = (float*)smem;         // 128 x 64 f32 overlays W pages in epilogue
    const int t = threadIdx.x;
    const int w = t >> 6, l = t & 63;
    const int e0 = blockIdx.x * 128;

    if (t < 128) sdst[t] = dst[e0 + t];
    // stage W page 0 (cols 0..63); note (64+cc)&15 == cc&15 so both pages share swizzle
    #pragma unroll
    for (int i = 0; i < 4; ++i) {
        int cid = i * 256 + t;                 // 0..1023
        int cc = cid >> 4, ch = cid & 15;
        int sc = ch ^ (cc & 15);
        uint4 vh = *(const uint4*)(w2hi + (size_t)cc * DH + sc * 8);
        uint4 vl = *(const uint4*)(w2lo + (size_t)cc * DH + sc * 8);
        *(uint4*)(smem + cid * 16) = vh;
        *(uint4*)(smem + 16384 + cid * 16) = vl;
    }

    // gather + relu + split (cvt_pk) into A-fragments for both row-subtiles
    bf16x8 ahi[2][4], alo[2][4];
    #pragma unroll
    for (int rt = 0; rt < 2; ++rt) {
        int er = w * 32 + rt * 16 + (l & 15);
        int dn = dst[e0 + er], sn = src[e0 + er];
        const float* pa = Afp + (size_t)dn * DH + 8 * (l >> 4);
        const float* pb = Bfp + (size_t)sn * DH + 8 * (l >> 4);
        #pragma unroll
        for (int ks = 0; ks < 4; ++ks) {
            float4 a0 = *(const float4*)(pa + ks * 32);
            float4 a1 = *(const float4*)(pa + ks * 32 + 4);
            float4 b0 = *(const float4*)(pb + ks * 32);
            float4 b1 = *(const float4*)(pb + ks * 32 + 4);
            float v0 = fmaxf(a0.x + b0.x, 0.f), v1 = fmaxf(a0.y + b0.y, 0.f);
            float v2 = fmaxf(a0.z + b0.z, 0.f), v3 = fmaxf(a0.w + b0.w, 0.f);
            float v4 = fmaxf(a1.x + b1.x, 0.f), v5 = fmaxf(a1.y + b1.y, 0.f);
            float v6 = fmaxf(a1.z + b1.z, 0.f), v7 = fmaxf(a1.w + b1.w, 0.f);
            unsigned h01 = cvtpk(v0, v1), h23 = cvtpk(v2, v3);
            unsigned h45 = cvtpk(v4, v5), h67 = cvtpk(v6, v7);
            float l0 = v0 - __uint_as_float(h01 << 16);
            float l1 = v1 - __uint_as_float(h01 & 0xffff0000u);
            float l2 = v2 - __uint_as_float(h23 << 16);
            float l3 = v3 - __uint_as_float(h23 & 0xffff0000u);
            float l4 = v4 - __uint_as_float(h45 << 16);
            float l5 = v5 - __uint_as_float(h45 & 0xffff0000u);
            float l6 = v6 - __uint_as_float(h67 << 16);
            float l7 = v7 - __uint_as_float(h67 & 0xffff0000u);
            unsigned q01 = cvtpk(l0, l1), q23 = cvtpk(l2, l3);
            unsigned q45 = cvtpk(l4, l5), q67 = cvtpk(l6, l7);
            uint4 hp = {h01, h23, h45, h67};
            uint4 lp = {q01, q23, q45, q67};
            ahi[rt][ks] = *(bf16x8*)&hp;
            alo[rt][ks] = *(bf16x8*)&lp;
        }
    }
    f32x4 acc[2][8];
    #pragma unroll
    for (int rt = 0; rt < 2; ++rt)
        #pragma unroll
        for (int ct = 0; ct < 8; ++ct) acc[rt][ct] = (f32x4){0.f, 0.f, 0.f, 0.f};
    __syncthreads();
    // phase 0: cols 0..63 (ct 0..3)
    #pragma unroll
    for (int ct = 0; ct < 4; ++ct) {
        int colv = ct * 16 + (l & 15);
        #pragma unroll
        for (int ks = 0; ks < 4; ++ks) {
            int chb = ks * 4 + (l >> 4);
            int addr = colv * 256 + ((chb ^ (colv & 15)) << 4);
            bf16x8 bh = *(const bf16x8*)(smem + addr);
            bf16x8 bl = *(const bf16x8*)(smem + 16384 + addr);
            #pragma unroll
            for (int rt = 0; rt < 2; ++rt) {
                acc[rt][ct] = __builtin_amdgcn_mfma_f32_16x16x32_bf16(ahi[rt][ks], bh, acc[rt][ct], 0, 0, 0);
                acc[rt][ct] = __builtin_amdgcn_mfma_f32_16x16x32_bf16(ahi[rt][ks], bl, acc[rt][ct], 0, 0, 0);
                acc[rt][ct] = __builtin_amdgcn_mfma_f32_16x16x32_bf16(alo[rt][ks], bh, acc[rt][ct], 0, 0, 0);
            }
        }
    }
    __syncthreads();
    // stage W page 1 (cols 64..127) over the same LDS
    #pragma unroll
    for (int i = 0; i < 4; ++i) {
        int cid = i * 256 + t;
        int cc = cid >> 4, ch = cid & 15;
        int sc = ch ^ (cc & 15);
        uint4 vh = *(const uint4*)(w2hi + (size_t)(64 + cc) * DH + sc * 8);
        uint4 vl = *(const uint4*)(w2lo + (size_t)(64 + cc) * DH + sc * 8);
        *(uint4*)(smem + cid * 16) = vh;
        *(uint4*)(smem + 16384 + cid * 16) = vl;
    }
    __syncthreads();
    // phase 1: cols 64..127 (ct 4..7)
    #pragma unroll
    for (int ct = 4; ct < 8; ++ct) {
        int colv = ct * 16 + (l & 15);
        #pragma unroll
        for (int ks = 0; ks < 4; ++ks) {
            int chb = ks * 4 + (l >> 4);
            int addr = (colv & 63) * 256 + ((chb ^ (colv & 15)) << 4);
            bf16x8 bh = *(const bf16x8*)(smem + addr);
            bf16x8 bl = *(const bf16x8*)(smem + 16384 + addr);
            #pragma unroll
            for (int rt = 0; rt < 2; ++rt) {
                acc[rt][ct] = __builtin_amdgcn_mfma_f32_16x16x32_bf16(ahi[rt][ks], bh, acc[rt][ct], 0, 0, 0);
                acc[rt][ct] = __builtin_amdgcn_mfma_f32_16x16x32_bf16(ahi[rt][ks], bl, acc[rt][ct], 0, 0, 0);
                acc[rt][ct] = __builtin_amdgcn_mfma_f32_16x16x32_bf16(alo[rt][ks], bh, acc[rt][ct], 0, 0, 0);
            }
        }
    }
    // segmented max: 2 phases (64 cols each); R = 128x64 f32 overlays W pages
    #pragma unroll
    for (int chh = 0; chh < 2; ++chh) {
        __syncthreads();
        #pragma unroll
        for (int rt = 0; rt < 2; ++rt)
            #pragma unroll
            for (int c4 = 0; c4 < 4; ++c4) {
                int ct = chh * 4 + c4;
                int col64 = c4 * 16 + (l & 15);
                #pragma unroll
                for (int i = 0; i < 4; ++i) {
                    int row = w * 32 + rt * 16 + (l >> 4) * 4 + i;
                    R[row * 64 + (col64 ^ (((row >> 2) & 3) << 4))] = acc[rt][ct][i];
                }
            }
        __syncthreads();
        const int col = l;
        const int r0 = w * 32;
        float run = R[r0 * 64 + (col ^ (((r0 >> 2) & 3) << 4))];
        int cur = sdst[r0];
        #pragma unroll
        for (int rr = r0 + 1; rr < r0 + 32; ++rr) {
            float x = R[rr * 64 + (col ^ (((rr >> 2) & 3) << 4))];
            int dd = sdst[rr];
            if (dd != cur) {
                atomicMax(&agg[(size_t)cur * DH + chh * 64 + col], enc_f(run));
                cur = dd; run = x;
            } else {
                run = fmaxf(run, x);
            }
        }
        atomicMax(&agg[(size_t)cur * DH + chh * 64 + col], enc_f(run));
    }
}

// mode 0: h = relu(agg+b2) -> packed (hi|lo) in place; mode 1: out = agg+b2 fp32
__global__ void finalize_kernel(unsigned* agg, const float* __restrict__ b2,
                                unsigned* hpk, float* __restrict__ outf, int n, int mode) {
    int i = blockIdx.x * blockDim.x + threadIdx.x;
    int stride = gridDim.x * blockDim.x;
    for (; i < n; i += stride) {
        unsigned uv = agg[i];
        float f = (uv == ENC_NEG_INF) ? 0.0f : dec_f(uv) + b2[i & (DH - 1)];
        if (mode == 0) {
            f = fmaxf(f, 0.0f);
            ushort_t hi = f2bf(f);
            ushort_t lo = f2bf(f - bf2f(hi));
            hpk[i] = (unsigned)hi | ((unsigned)lo << 16);
        } else {
            outf[i] = f;
        }
    }
}

extern "C" void kernel_launch(void* const* d_in, const int* in_sizes, int n_in,
                              void* d_out, int out_size, void* d_ws, size_t ws_size,
                              hipStream_t stream) {
    const float* z  = (const float*)d_in[0];
    const int*   ei = (const int*)d_in[1];
    const float* W1 = (const float*)d_in[2];
    const float* b1 = (const float*)d_in[3];
    const float* W2 = (const float*)d_in[4];
    const float* b2 = (const float*)d_in[5];
    const int N = 50000, D = DH, E = 800000;
    const int* srcp = ei;
    const int* dstp = ei + E;

    float* Abuf = (float*)d_ws;
    float* Bbuf = Abuf + (size_t)N * D;
    unsigned* agg = (unsigned*)(Bbuf + (size_t)N * D);
    ushort_t* W1t_hi = (ushort_t*)(agg + (size_t)N * D);
    ushort_t* W1t_lo = W1t_hi + NLAYER * 256 * D;
    ushort_t* W2t_hi = W1t_lo + NLAYER * 256 * D;
    ushort_t* W2t_lo = W2t_hi + NLAYER * D * D;
    unsigned* cnt = (unsigned*)(W2t_lo + NLAYER * D * D);
    unsigned* off = cnt + N;
    unsigned* bsum = off + N;
    int* s_src = (int*)(bsum + 64);
    int* s_dst = s_src + E;
    float* outp = (float*)d_out;

    convert_w<<<128, 256, 0, stream>>>(W1, W2, W1t_hi, W1t_lo, W2t_hi, W2t_lo);
    convert_h<<<1024, 256, 0, stream>>>(z, agg, N * D);   // packed h lives in agg buffer

    const int NB = (N + 1023) / 1024;   // 49
    fill_u<<<256, 256, 0, stream>>>(cnt, N, 0u);
    hist_kernel<<<1024, 256, 0, stream>>>(dstp, cnt, E);
    scan_local<<<NB, 1024, 0, stream>>>(cnt, off, bsum, N);
    scan_base<<<1, 64, 0, stream>>>(bsum, NB);
    scan_add<<<256, 256, 0, stream>>>(off, bsum, cnt, N);
    scatter_kernel<<<1024, 256, 0, stream>>>(srcp, dstp, off, cnt, s_src, s_dst, E);

    const int nrb = (N + 127) / 128;
    for (int l = 0; l < NLAYER; ++l) {
        node_gemm<<<2 * nrb, 256, 0, stream>>>(agg,
                                               W1t_hi + ((size_t)l * 256) * D,
                                               W1t_lo + ((size_t)l * 256) * D,
                                               b1 + (size_t)l * D, Abuf, Bbuf, N, nrb);
        fill_u<<<2048, 256, 0, stream>>>(agg, N * D, ENC_NEG_INF);
        edge_mlp<<<E / 128, 256, 0, stream>>>(Abuf, Bbuf, s_src, s_dst,
                                              W2t_hi + (size_t)l * D * D,
                                              W2t_lo + (size_t)l * D * D, agg, E);
        finalize_kernel<<<2048, 256, 0, stream>>>(agg, b2 + (size_t)l * D,
                                                  agg, outp, N * D,
                                                  (l < NLAYER - 1) ? 0 : 1);
    }
}

// Round 10
// 753.203 us; speedup vs baseline: 3.0062x; 1.0386x over previous
//
#include <hip/hip_runtime.h>

#define DH 128
#define NLAYER 3
typedef unsigned short ushort_t;
typedef __attribute__((ext_vector_type(8))) short bf16x8;
typedef __attribute__((ext_vector_type(4))) float f32x4;

// ---- bf16 split helpers (RNE) ----
__device__ __forceinline__ ushort_t f2bf(float a) {
    unsigned u = __float_as_uint(a);
    return (ushort_t)((u + 0x7fffu + ((u >> 16) & 1u)) >> 16);
}
__device__ __forceinline__ float bf2f(ushort_t h) {
    return __uint_as_float(((unsigned)h) << 16);
}
// pack 2 f32 -> 2 bf16 (low16=cvt(a), high16=cvt(b)); residual computed from returned bits
__device__ __forceinline__ unsigned cvtpk(float a, float b) {
    unsigned r;
    asm("v_cvt_pk_bf16_f32 %0, %1, %2" : "=v"(r) : "v"(a), "v"(b));
    return r;
}

// ---- sortable-uint encoding for float atomic max ----
__device__ __forceinline__ unsigned enc_f(float f) {
    unsigned u = __float_as_uint(f);
    return (u & 0x80000000u) ? ~u : (u | 0x80000000u);
}
__device__ __forceinline__ float dec_f(unsigned u) {
    unsigned b = (u & 0x80000000u) ? (u ^ 0x80000000u) : ~u;
    return __uint_as_float(b);
}
#define ENC_NEG_INF 0x007FFFFFu

__global__ void fill_u(unsigned* __restrict__ p, int n, unsigned v) {
    int i = blockIdx.x * blockDim.x + threadIdx.x;
    int stride = gridDim.x * blockDim.x;
    for (; i < n; i += stride) p[i] = v;
}

__global__ void hist_kernel(const int* __restrict__ dst, unsigned* __restrict__ cnt, int E) {
    int e = blockIdx.x * blockDim.x + threadIdx.x;
    int stride = gridDim.x * blockDim.x;
    for (; e < E; e += stride) atomicAdd(&cnt[dst[e]], 1u);
}

// ---- multi-block scan: local scan -> base scan -> add+zero ----
__global__ __launch_bounds__(1024) void scan_local(const unsigned* __restrict__ cnt,
                                                   unsigned* __restrict__ off,
                                                   unsigned* __restrict__ bsum, int n) {
    __shared__ unsigned s[1024];
    const int t = threadIdx.x;
    int idx = blockIdx.x * 1024 + t;
    unsigned v = (idx < n) ? cnt[idx] : 0u;
    s[t] = v;
    __syncthreads();
    for (int d = 1; d < 1024; d <<= 1) {
        unsigned u = (t >= d) ? s[t - d] : 0u;
        __syncthreads();
        s[t] += u;
        __syncthreads();
    }
    if (idx < n) off[idx] = s[t] - v;
    if (t == 1023) bsum[blockIdx.x] = s[t];
}
__global__ void scan_base(unsigned* __restrict__ bsum, int nb) {
    __shared__ unsigned s[64];
    const int t = threadIdx.x;
    unsigned v = (t < nb) ? bsum[t] : 0u;
    s[t] = v;
    __syncthreads();
    for (int d = 1; d < 64; d <<= 1) {
        unsigned u = (t >= d) ? s[t - d] : 0u;
        __syncthreads();
        s[t] += u;
        __syncthreads();
    }
    if (t < nb) bsum[t] = s[t] - v;
}
__global__ void scan_add(unsigned* __restrict__ off, const unsigned* __restrict__ bsum,
                         unsigned* __restrict__ cnt, int n) {
    int i = blockIdx.x * blockDim.x + threadIdx.x;
    int stride = gridDim.x * blockDim.x;
    for (; i < n; i += stride) { off[i] += bsum[i >> 10]; cnt[i] = 0u; }
}

__global__ void scatter_kernel(const int* __restrict__ src, const int* __restrict__ dst,
                               const unsigned* __restrict__ off, unsigned* __restrict__ cur,
                               int* __restrict__ s_src, int* __restrict__ s_dst, int E) {
    int e = blockIdx.x * blockDim.x + threadIdx.x;
    int stride = gridDim.x * blockDim.x;
    for (; e < E; e += stride) {
        int d = dst[e];
        unsigned p = off[d] + atomicAdd(&cur[d], 1u);
        s_src[p] = src[e];
        s_dst[p] = d;
    }
}

// W1t[l][c'][k]: c'<128 -> A-cols (W1[l][k][c']), c'>=128 -> B-cols (W1[l][128+k][c'-128])
// W2t[l][c][k] = W2[l][k][c]. All split into hi/lo bf16.
__global__ void convert_w(const float* __restrict__ W1, const float* __restrict__ W2,
                          ushort_t* __restrict__ W1t_hi, ushort_t* __restrict__ W1t_lo,
                          ushort_t* __restrict__ W2t_hi, ushort_t* __restrict__ W2t_lo) {
    const int T1 = NLAYER * 256 * DH, T2 = NLAYER * DH * DH;
    int i = blockIdx.x * blockDim.x + threadIdx.x;
    int stride = gridDim.x * blockDim.x;
    for (; i < T1 + T2; i += stride) {
        if (i < T1) {
            int l = i >> 15, r = i & 32767, c = r >> 7, k = r & 127;
            float w = W1[(size_t)l * 32768 + (size_t)((c < 128) ? k : 128 + k) * DH + (c & 127)];
            ushort_t hi = f2bf(w);
            W1t_hi[i] = hi; W1t_lo[i] = f2bf(w - bf2f(hi));
        } else {
            int j = i - T1;
            int l = j >> 14, r = j & 16383, c = r >> 7, k = r & 127;
            float w = W2[(size_t)l * 16384 + (size_t)k * DH + c];
            ushort_t hi = f2bf(w);
            W2t_hi[j] = hi; W2t_lo[j] = f2bf(w - bf2f(hi));
        }
    }
}

// node GEMM v2: W paged in two 64-col halves (33KB LDS); input decoded inline.
// mode 0: read z fp32 raw.  mode 1: read agg enc-u32, f=(empty?0:dec+b2prev), relu.
// Grid 2*nrb: blocks [0,nrb) -> A half (+b1 bias), [nrb,2nrb) -> B half.
__global__ __launch_bounds__(256, 2) void node_gemm(
    const float* __restrict__ zin, const unsigned* __restrict__ aggin,
    const float* __restrict__ b2prev,
    const ushort_t* __restrict__ wthi, const ushort_t* __restrict__ wtlo,
    const float* __restrict__ b1, float* __restrict__ outA, float* __restrict__ outB,
    int N, int nrb, int mode) {
    __shared__ char smem[33280];     // W page hi 16K | lo 16K | b2s 512B
    float* b2s = (float*)(smem + 32768);
    const int t = threadIdx.x;
    const int w = t >> 6, l = t & 63;
    const int bb = blockIdx.x;
    const int half = (bb >= nrb) ? 1 : 0;
    const ushort_t* whi = wthi + (size_t)(half ? 128 : 0) * DH;
    const ushort_t* wlo = wtlo + (size_t)(half ? 128 : 0) * DH;
    float* outp = half ? outB : outA;
    const int n0 = (bb - half * nrb) * 128;

    if (t < 128) b2s[t] = mode ? b2prev[t] : 0.0f;
    // stage W page 0 (cols 0..63 of this half)
    #pragma unroll
    for (int i = 0; i < 4; ++i) {
        int cid = i * 256 + t;
        int cc = cid >> 4, ch = cid & 15;
        int sc = ch ^ (cc & 15);
        uint4 vh = *(const uint4*)(whi + (size_t)cc * DH + sc * 8);
        uint4 vl = *(const uint4*)(wlo + (size_t)cc * DH + sc * 8);
        *(uint4*)(smem + cid * 16) = vh;
        *(uint4*)(smem + 16384 + cid * 16) = vl;
    }
    __syncthreads();

    // load + decode + split input fragments (both row subtiles)
    bf16x8 ahi[2][4], alo[2][4];
    #pragma unroll
    for (int rt = 0; rt < 2; ++rt) {
        int row = n0 + w * 32 + rt * 16 + (l & 15);
        if (row >= N) row = N - 1;
        size_t base = (size_t)row * DH + 8 * (l >> 4);
        const int kbase = 8 * (l >> 4);
        #pragma unroll
        for (int ks = 0; ks < 4; ++ks) {
            float v0, v1, v2, v3, v4, v5, v6, v7;
            if (mode == 0) {
                float4 a0 = *(const float4*)(zin + base + ks * 32);
                float4 a1 = *(const float4*)(zin + base + ks * 32 + 4);
                v0 = a0.x; v1 = a0.y; v2 = a0.z; v3 = a0.w;
                v4 = a1.x; v5 = a1.y; v6 = a1.z; v7 = a1.w;
            } else {
                uint4 u0 = *(const uint4*)(aggin + base + ks * 32);
                uint4 u1 = *(const uint4*)(aggin + base + ks * 32 + 4);
                float4 c0 = *(const float4*)&b2s[kbase + ks * 32];
                float4 c1 = *(const float4*)&b2s[kbase + ks * 32 + 4];
                v0 = fmaxf((u0.x == ENC_NEG_INF) ? 0.0f : dec_f(u0.x) + c0.x, 0.0f);
                v1 = fmaxf((u0.y == ENC_NEG_INF) ? 0.0f : dec_f(u0.y) + c0.y, 0.0f);
                v2 = fmaxf((u0.z == ENC_NEG_INF) ? 0.0f : dec_f(u0.z) + c0.z, 0.0f);
                v3 = fmaxf((u0.w == ENC_NEG_INF) ? 0.0f : dec_f(u0.w) + c0.w, 0.0f);
                v4 = fmaxf((u1.x == ENC_NEG_INF) ? 0.0f : dec_f(u1.x) + c1.x, 0.0f);
                v5 = fmaxf((u1.y == ENC_NEG_INF) ? 0.0f : dec_f(u1.y) + c1.y, 0.0f);
                v6 = fmaxf((u1.z == ENC_NEG_INF) ? 0.0f : dec_f(u1.z) + c1.z, 0.0f);
                v7 = fmaxf((u1.w == ENC_NEG_INF) ? 0.0f : dec_f(u1.w) + c1.w, 0.0f);
            }
            unsigned h01 = cvtpk(v0, v1), h23 = cvtpk(v2, v3);
            unsigned h45 = cvtpk(v4, v5), h67 = cvtpk(v6, v7);
            float l0 = v0 - __uint_as_float(h01 << 16);
            float l1 = v1 - __uint_as_float(h01 & 0xffff0000u);
            float l2 = v2 - __uint_as_float(h23 << 16);
            float l3 = v3 - __uint_as_float(h23 & 0xffff0000u);
            float l4 = v4 - __uint_as_float(h45 << 16);
            float l5 = v5 - __uint_as_float(h45 & 0xffff0000u);
            float l6 = v6 - __uint_as_float(h67 << 16);
            float l7 = v7 - __uint_as_float(h67 & 0xffff0000u);
            unsigned q01 = cvtpk(l0, l1), q23 = cvtpk(l2, l3);
            unsigned q45 = cvtpk(l4, l5), q67 = cvtpk(l6, l7);
            uint4 hp = {h01, h23, h45, h67};
            uint4 lp = {q01, q23, q45, q67};
            ahi[rt][ks] = *(bf16x8*)&hp;
            alo[rt][ks] = *(bf16x8*)&lp;
        }
    }
    f32x4 acc[2][8];
    #pragma unroll
    for (int rt = 0; rt < 2; ++rt)
        #pragma unroll
        for (int ct = 0; ct < 8; ++ct) acc[rt][ct] = (f32x4){0.f, 0.f, 0.f, 0.f};
    // phase 0: cols 0..63 (ct 0..3)
    #pragma unroll
    for (int ct = 0; ct < 4; ++ct) {
        int colv = ct * 16 + (l & 15);
        #pragma unroll
        for (int ks = 0; ks < 4; ++ks) {
            int chb = ks * 4 + (l >> 4);
            int addr = colv * 256 + ((chb ^ (colv & 15)) << 4);
            bf16x8 bh = *(const bf16x8*)(smem + addr);
            bf16x8 bl = *(const bf16x8*)(smem + 16384 + addr);
            #pragma unroll
            for (int rt = 0; rt < 2; ++rt) {
                acc[rt][ct] = __builtin_amdgcn_mfma_f32_16x16x32_bf16(ahi[rt][ks], bh, acc[rt][ct], 0, 0, 0);
                acc[rt][ct] = __builtin_amdgcn_mfma_f32_16x16x32_bf16(ahi[rt][ks], bl, acc[rt][ct], 0, 0, 0);
                acc[rt][ct] = __builtin_amdgcn_mfma_f32_16x16x32_bf16(alo[rt][ks], bh, acc[rt][ct], 0, 0, 0);
            }
        }
    }
    __syncthreads();
    // stage W page 1 (cols 64..127 of this half)
    #pragma unroll
    for (int i = 0; i < 4; ++i) {
        int cid = i * 256 + t;
        int cc = cid >> 4, ch = cid & 15;
        int sc = ch ^ (cc & 15);
        uint4 vh = *(const uint4*)(whi + (size_t)(64 + cc) * DH + sc * 8);
        uint4 vl = *(const uint4*)(wlo + (size_t)(64 + cc) * DH + sc * 8);
        *(uint4*)(smem + cid * 16) = vh;
        *(uint4*)(smem + 16384 + cid * 16) = vl;
    }
    __syncthreads();
    // phase 1: cols 64..127 (ct 4..7)
    #pragma unroll
    for (int ct = 4; ct < 8; ++ct) {
        int colv = ct * 16 + (l & 15);
        #pragma unroll
        for (int ks = 0; ks < 4; ++ks) {
            int chb = ks * 4 + (l >> 4);
            int addr = (colv & 63) * 256 + ((chb ^ (colv & 15)) << 4);
            bf16x8 bh = *(const bf16x8*)(smem + addr);
            bf16x8 bl = *(const bf16x8*)(smem + 16384 + addr);
            #pragma unroll
            for (int rt = 0; rt < 2; ++rt) {
                acc[rt][ct] = __builtin_amdgcn_mfma_f32_16x16x32_bf16(ahi[rt][ks], bh, acc[rt][ct], 0, 0, 0);
                acc[rt][ct] = __builtin_amdgcn_mfma_f32_16x16x32_bf16(ahi[rt][ks], bl, acc[rt][ct], 0, 0, 0);
                acc[rt][ct] = __builtin_amdgcn_mfma_f32_16x16x32_bf16(alo[rt][ks], bh, acc[rt][ct], 0, 0, 0);
            }
        }
    }
    #pragma unroll
    for (int ct = 0; ct < 8; ++ct) {
        int col = ct * 16 + (l & 15);
        float bv = half ? 0.0f : b1[col];
        #pragma unroll
        for (int rt = 0; rt < 2; ++rt)
            #pragma unroll
            for (int i = 0; i < 4; ++i) {
                int row = n0 + w * 32 + rt * 16 + (l >> 4) * 4 + i;
                if (row < N) outp[(size_t)row * DH + col] = acc[rt][ct][i] + bv;
            }
    }
}

// Edge kernel v7 (unchanged): 128 sorted edges x 128 cols, 4 waves, W paged 33KB.
__global__ __launch_bounds__(256, 2) void edge_mlp(
    const float* __restrict__ Afp, const float* __restrict__ Bfp,
    const int* __restrict__ src, const int* __restrict__ dst,
    const ushort_t* __restrict__ w2hi, const ushort_t* __restrict__ w2lo,
    unsigned* __restrict__ agg, int E) {
    __shared__ char smem[33280];     // Whi page 16K | Wlo page 16K | sdst 512B
    int* sdst = (int*)(smem + 32768);
    float* R = (float*)smem;         // 128 x 64 f32 overlays W pages in epilogue
    const int t = threadIdx.x;
    const int w = t >> 6, l = t & 63;
    const int e0 = blockIdx.x * 128;

    if (t < 128) sdst[t] = dst[e0 + t];
    #pragma unroll
    for (int i = 0; i < 4; ++i) {
        int cid = i * 256 + t;
        int cc = cid >> 4, ch = cid & 15;
        int sc = ch ^ (cc & 15);
        uint4 vh = *(const uint4*)(w2hi + (size_t)cc * DH + sc * 8);
        uint4 vl = *(const uint4*)(w2lo + (size_t)cc * DH + sc * 8);
        *(uint4*)(smem + cid * 16) = vh;
        *(uint4*)(smem + 16384 + cid * 16) = vl;
    }

    bf16x8 ahi[2][4], alo[2][4];
    #pragma unroll
    for (int rt = 0; rt < 2; ++rt) {
        int er = w * 32 + rt * 16 + (l & 15);
        int dn = dst[e0 + er], sn = src[e0 + er];
        const float* pa = Afp + (size_t)dn * DH + 8 * (l >> 4);
        const float* pb = Bfp + (size_t)sn * DH + 8 * (l >> 4);
        #pragma unroll
        for (int ks = 0; ks < 4; ++ks) {
            float4 a0 = *(const float4*)(pa + ks * 32);
            float4 a1 = *(const float4*)(pa + ks * 32 + 4);
            float4 b0 = *(const float4*)(pb + ks * 32);
            float4 b1 = *(const float4*)(pb + ks * 32 + 4);
            float v0 = fmaxf(a0.x + b0.x, 0.f), v1 = fmaxf(a0.y + b0.y, 0.f);
            float v2 = fmaxf(a0.z + b0.z, 0.f), v3 = fmaxf(a0.w + b0.w, 0.f);
            float v4 = fmaxf(a1.x + b1.x, 0.f), v5 = fmaxf(a1.y + b1.y, 0.f);
            float v6 = fmaxf(a1.z + b1.z, 0.f), v7 = fmaxf(a1.w + b1.w, 0.f);
            unsigned h01 = cvtpk(v0, v1), h23 = cvtpk(v2, v3);
            unsigned h45 = cvtpk(v4, v5), h67 = cvtpk(v6, v7);
            float l0 = v0 - __uint_as_float(h01 << 16);
            float l1 = v1 - __uint_as_float(h01 & 0xffff0000u);
            float l2 = v2 - __uint_as_float(h23 << 16);
            float l3 = v3 - __uint_as_float(h23 & 0xffff0000u);
            float l4 = v4 - __uint_as_float(h45 << 16);
            float l5 = v5 - __uint_as_float(h45 & 0xffff0000u);
            float l6 = v6 - __uint_as_float(h67 << 16);
            float l7 = v7 - __uint_as_float(h67 & 0xffff0000u);
            unsigned q01 = cvtpk(l0, l1), q23 = cvtpk(l2, l3);
            unsigned q45 = cvtpk(l4, l5), q67 = cvtpk(l6, l7);
            uint4 hp = {h01, h23, h45, h67};
            uint4 lp = {q01, q23, q45, q67};
            ahi[rt][ks] = *(bf16x8*)&hp;
            alo[rt][ks] = *(bf16x8*)&lp;
        }
    }
    f32x4 acc[2][8];
    #pragma unroll
    for (int rt = 0; rt < 2; ++rt)
        #pragma unroll
        for (int ct = 0; ct < 8; ++ct) acc[rt][ct] = (f32x4){0.f, 0.f, 0.f, 0.f};
    __syncthreads();
    #pragma unroll
    for (int ct = 0; ct < 4; ++ct) {
        int colv = ct * 16 + (l & 15);
        #pragma unroll
        for (int ks = 0; ks < 4; ++ks) {
            int chb = ks * 4 + (l >> 4);
            int addr = colv * 256 + ((chb ^ (colv & 15)) << 4);
            bf16x8 bh = *(const bf16x8*)(smem + addr);
            bf16x8 bl = *(const bf16x8*)(smem + 16384 + addr);
            #pragma unroll
            for (int rt = 0; rt < 2; ++rt) {
                acc[rt][ct] = __builtin_amdgcn_mfma_f32_16x16x32_bf16(ahi[rt][ks], bh, acc[rt][ct], 0, 0, 0);
                acc[rt][ct] = __builtin_amdgcn_mfma_f32_16x16x32_bf16(ahi[rt][ks], bl, acc[rt][ct], 0, 0, 0);
                acc[rt][ct] = __builtin_amdgcn_mfma_f32_16x16x32_bf16(alo[rt][ks], bh, acc[rt][ct], 0, 0, 0);
            }
        }
    }
    __syncthreads();
    #pragma unroll
    for (int i = 0; i < 4; ++i) {
        int cid = i * 256 + t;
        int cc = cid >> 4, ch = cid & 15;
        int sc = ch ^ (cc & 15);
        uint4 vh = *(const uint4*)(w2hi + (size_t)(64 + cc) * DH + sc * 8);
        uint4 vl = *(const uint4*)(w2lo + (size_t)(64 + cc) * DH + sc * 8);
        *(uint4*)(smem + cid * 16) = vh;
        *(uint4*)(smem + 16384 + cid * 16) = vl;
    }
    __syncthreads();
    #pragma unroll
    for (int ct = 4; ct < 8; ++ct) {
        int colv = ct * 16 + (l & 15);
        #pragma unroll
        for (int ks = 0; ks < 4; ++ks) {
            int chb = ks * 4 + (l >> 4);
            int addr = (colv & 63) * 256 + ((chb ^ (colv & 15)) << 4);
            bf16x8 bh = *(const bf16x8*)(smem + addr);
            bf16x8 bl = *(const bf16x8*)(smem + 16384 + addr);
            #pragma unroll
            for (int rt = 0; rt < 2; ++rt) {
                acc[rt][ct] = __builtin_amdgcn_mfma_f32_16x16x32_bf16(ahi[rt][ks], bh, acc[rt][ct], 0, 0, 0);
                acc[rt][ct] = __builtin_amdgcn_mfma_f32_16x16x32_bf16(ahi[rt][ks], bl, acc[rt][ct], 0, 0, 0);
                acc[rt][ct] = __builtin_amdgcn_mfma_f32_16x16x32_bf16(alo[rt][ks], bh, acc[rt][ct], 0, 0, 0);
            }
        }
    }
    #pragma unroll
    for (int chh = 0; chh < 2; ++chh) {
        __syncthreads();
        #pragma unroll
        for (int rt = 0; rt < 2; ++rt)
            #pragma unroll
            for (int c4 = 0; c4 < 4; ++c4) {
                int ct = chh * 4 + c4;
                int col64 = c4 * 16 + (l & 15);
                #pragma unroll
                for (int i = 0; i < 4; ++i) {
                    int row = w * 32 + rt * 16 + (l >> 4) * 4 + i;
                    R[row * 64 + (col64 ^ (((row >> 2) & 3) << 4))] = acc[rt][ct][i];
                }
            }
        __syncthreads();
        const int col = l;
        const int r0 = w * 32;
        float run = R[r0 * 64 + (col ^ (((r0 >> 2) & 3) << 4))];
        int cur = sdst[r0];
        #pragma unroll
        for (int rr = r0 + 1; rr < r0 + 32; ++rr) {
            float x = R[rr * 64 + (col ^ (((rr >> 2) & 3) << 4))];
            int dd = sdst[rr];
            if (dd != cur) {
                atomicMax(&agg[(size_t)cur * DH + chh * 64 + col], enc_f(run));
                cur = dd; run = x;
            } else {
                run = fmaxf(run, x);
            }
        }
        atomicMax(&agg[(size_t)cur * DH + chh * 64 + col], enc_f(run));
    }
}

// final-layer output: out = (agg empty ? 0 : dec(agg) + b2[col]) fp32, no relu
__global__ void finalize_kernel(const unsigned* __restrict__ agg, const float* __restrict__ b2,
                                float* __restrict__ outf, int n) {
    int i = blockIdx.x * blockDim.x + threadIdx.x;
    int stride = gridDim.x * blockDim.x;
    for (; i < n; i += stride) {
        unsigned uv = agg[i];
        outf[i] = (uv == ENC_NEG_INF) ? 0.0f : dec_f(uv) + b2[i & (DH - 1)];
    }
}

extern "C" void kernel_launch(void* const* d_in, const int* in_sizes, int n_in,
                              void* d_out, int out_size, void* d_ws, size_t ws_size,
                              hipStream_t stream) {
    const float* z  = (const float*)d_in[0];
    const int*   ei = (const int*)d_in[1];
    const float* W1 = (const float*)d_in[2];
    const float* b1 = (const float*)d_in[3];
    const float* W2 = (const float*)d_in[4];
    const float* b2 = (const float*)d_in[5];
    const int N = 50000, D = DH, E = 800000;
    const int* srcp = ei;
    const int* dstp = ei + E;

    float* Abuf = (float*)d_ws;
    float* Bbuf = Abuf + (size_t)N * D;
    unsigned* agg = (unsigned*)(Bbuf + (size_t)N * D);
    ushort_t* W1t_hi = (ushort_t*)(agg + (size_t)N * D);
    ushort_t* W1t_lo = W1t_hi + NLAYER * 256 * D;
    ushort_t* W2t_hi = W1t_lo + NLAYER * 256 * D;
    ushort_t* W2t_lo = W2t_hi + NLAYER * D * D;
    unsigned* cnt = (unsigned*)(W2t_lo + NLAYER * D * D);
    unsigned* off = cnt + N;
    unsigned* bsum = off + N;
    int* s_src = (int*)(bsum + 64);
    int* s_dst = s_src + E;
    float* outp = (float*)d_out;

    convert_w<<<128, 256, 0, stream>>>(W1, W2, W1t_hi, W1t_lo, W2t_hi, W2t_lo);

    const int NB = (N + 1023) / 1024;   // 49
    fill_u<<<256, 256, 0, stream>>>(cnt, N, 0u);
    hist_kernel<<<1024, 256, 0, stream>>>(dstp, cnt, E);
    scan_local<<<NB, 1024, 0, stream>>>(cnt, off, bsum, N);
    scan_base<<<1, 64, 0, stream>>>(bsum, NB);
    scan_add<<<256, 256, 0, stream>>>(off, bsum, cnt, N);
    scatter_kernel<<<1024, 256, 0, stream>>>(srcp, dstp, off, cnt, s_src, s_dst, E);

    const int nrb = (N + 127) / 128;
    for (int l = 0; l < NLAYER; ++l) {
        // node_gemm reads agg of previous layer (or z for l=0), then agg is reset
        node_gemm<<<2 * nrb, 256, 0, stream>>>(z, agg,
                                               (l > 0) ? (b2 + (size_t)(l - 1) * D) : nullptr,
                                               W1t_hi + ((size_t)l * 256) * D,
                                               W1t_lo + ((size_t)l * 256) * D,
                                               b1 + (size_t)l * D, Abuf, Bbuf,
                                               N, nrb, (l > 0) ? 1 : 0);
        fill_u<<<2048, 256, 0, stream>>>(agg, N * D, ENC_NEG_INF);
        edge_mlp<<<E / 128, 256, 0, stream>>>(Abuf, Bbuf, s_src, s_dst,
                                              W2t_hi + (size_t)l * D * D,
                                              W2t_lo + (size_t)l * D * D, agg, E);
    }
    finalize_kernel<<<2048, 256, 0, stream>>>(agg, b2 + (size_t)2 * D, outp, N * D);
}

// Round 13
// 748.450 us; speedup vs baseline: 3.0253x; 1.0064x over previous
//
#include <hip/hip_runtime.h>

#define DH 128
#define NLAYER 3
typedef unsigned short ushort_t;
typedef __attribute__((ext_vector_type(8))) short bf16x8;
typedef __attribute__((ext_vector_type(4))) float f32x4;

// ---- bf16 split helpers (RNE) ----
__device__ __forceinline__ ushort_t f2bf(float a) {
    unsigned u = __float_as_uint(a);
    return (ushort_t)((u + 0x7fffu + ((u >> 16) & 1u)) >> 16);
}
__device__ __forceinline__ float bf2f(ushort_t h) {
    return __uint_as_float(((unsigned)h) << 16);
}
// pack 2 f32 -> 2 bf16 (low16=cvt(a), high16=cvt(b)); residual computed from returned bits
__device__ __forceinline__ unsigned cvtpk(float a, float b) {
    unsigned r;
    asm("v_cvt_pk_bf16_f32 %0, %1, %2" : "=v"(r) : "v"(a), "v"(b));
    return r;
}

// ---- sortable-uint encoding for float atomic max ----
__device__ __forceinline__ unsigned enc_f(float f) {
    unsigned u = __float_as_uint(f);
    return (u & 0x80000000u) ? ~u : (u | 0x80000000u);
}
__device__ __forceinline__ float dec_f(unsigned u) {
    unsigned b = (u & 0x80000000u) ? (u ^ 0x80000000u) : ~u;
    return __uint_as_float(b);
}
#define ENC_NEG_INF 0x007FFFFFu

__global__ void fill_u(unsigned* __restrict__ p, int n, unsigned v) {
    int i = blockIdx.x * blockDim.x + threadIdx.x;
    int stride = gridDim.x * blockDim.x;
    for (; i < n; i += stride) p[i] = v;
}

__global__ void hist_kernel(const int* __restrict__ dst, unsigned* __restrict__ cnt, int E) {
    int e = blockIdx.x * blockDim.x + threadIdx.x;
    int stride = gridDim.x * blockDim.x;
    for (; e < E; e += stride) atomicAdd(&cnt[dst[e]], 1u);
}

// ---- multi-block scan: local scan -> base scan -> add+zero ----
__global__ __launch_bounds__(1024) void scan_local(const unsigned* __restrict__ cnt,
                                                   unsigned* __restrict__ off,
                                                   unsigned* __restrict__ bsum, int n) {
    __shared__ unsigned s[1024];
    const int t = threadIdx.x;
    int idx = blockIdx.x * 1024 + t;
    unsigned v = (idx < n) ? cnt[idx] : 0u;
    s[t] = v;
    __syncthreads();
    for (int d = 1; d < 1024; d <<= 1) {
        unsigned u = (t >= d) ? s[t - d] : 0u;
        __syncthreads();
        s[t] += u;
        __syncthreads();
    }
    if (idx < n) off[idx] = s[t] - v;
    if (t == 1023) bsum[blockIdx.x] = s[t];
}
__global__ void scan_base(unsigned* __restrict__ bsum, int nb) {
    __shared__ unsigned s[64];
    const int t = threadIdx.x;
    unsigned v = (t < nb) ? bsum[t] : 0u;
    s[t] = v;
    __syncthreads();
    for (int d = 1; d < 64; d <<= 1) {
        unsigned u = (t >= d) ? s[t - d] : 0u;
        __syncthreads();
        s[t] += u;
        __syncthreads();
    }
    if (t < nb) bsum[t] = s[t] - v;
}
__global__ void scan_add(unsigned* __restrict__ off, const unsigned* __restrict__ bsum,
                         unsigned* __restrict__ cnt, int n) {
    int i = blockIdx.x * blockDim.x + threadIdx.x;
    int stride = gridDim.x * blockDim.x;
    for (; i < n; i += stride) { off[i] += bsum[i >> 10]; cnt[i] = 0u; }
}

__global__ void scatter_kernel(const int* __restrict__ src, const int* __restrict__ dst,
                               const unsigned* __restrict__ off, unsigned* __restrict__ cur,
                               int* __restrict__ s_src, int* __restrict__ s_dst, int E) {
    int e = blockIdx.x * blockDim.x + threadIdx.x;
    int stride = gridDim.x * blockDim.x;
    for (; e < E; e += stride) {
        int d = dst[e];
        unsigned p = off[d] + atomicAdd(&cur[d], 1u);
        s_src[p] = src[e];
        s_dst[p] = d;
    }
}

// W1t[l][c'][k]: c'<128 -> A-cols (W1[l][k][c']), c'>=128 -> B-cols (W1[l][128+k][c'-128])
// W2t[l][c][k] = W2[l][k][c]. All split into hi/lo bf16.
__global__ void convert_w(const float* __restrict__ W1, const float* __restrict__ W2,
                          ushort_t* __restrict__ W1t_hi, ushort_t* __restrict__ W1t_lo,
                          ushort_t* __restrict__ W2t_hi, ushort_t* __restrict__ W2t_lo) {
    const int T1 = NLAYER * 256 * DH, T2 = NLAYER * DH * DH;
    int i = blockIdx.x * blockDim.x + threadIdx.x;
    int stride = gridDim.x * blockDim.x;
    for (; i < T1 + T2; i += stride) {
        if (i < T1) {
            int l = i >> 15, r = i & 32767, c = r >> 7, k = r & 127;
            float w = W1[(size_t)l * 32768 + (size_t)((c < 128) ? k : 128 + k) * DH + (c & 127)];
            ushort_t hi = f2bf(w);
            W1t_hi[i] = hi; W1t_lo[i] = f2bf(w - bf2f(hi));
        } else {
            int j = i - T1;
            int l = j >> 14, r = j & 16383, c = r >> 7, k = r & 127;
            float w = W2[(size_t)l * 16384 + (size_t)k * DH + c];
            ushort_t hi = f2bf(w);
            W2t_hi[j] = hi; W2t_lo[j] = f2bf(w - bf2f(hi));
        }
    }
}

// node GEMM v2 (unchanged): W paged in two 64-col halves (33KB LDS); input decoded inline.
// mode 0: read z fp32 raw.  mode 1: read agg enc-u32, f=(empty?0:dec+b2prev), relu.
// Grid 2*nrb: blocks [0,nrb) -> A half (+b1 bias), [nrb,2nrb) -> B half.
__global__ __launch_bounds__(256, 2) void node_gemm(
    const float* __restrict__ zin, const unsigned* __restrict__ aggin,
    const float* __restrict__ b2prev,
    const ushort_t* __restrict__ wthi, const ushort_t* __restrict__ wtlo,
    const float* __restrict__ b1, float* __restrict__ outA, float* __restrict__ outB,
    int N, int nrb, int mode) {
    __shared__ char smem[33280];     // W page hi 16K | lo 16K | b2s 512B
    float* b2s = (float*)(smem + 32768);
    const int t = threadIdx.x;
    const int w = t >> 6, l = t & 63;
    const int bb = blockIdx.x;
    const int half = (bb >= nrb) ? 1 : 0;
    const ushort_t* whi = wthi + (size_t)(half ? 128 : 0) * DH;
    const ushort_t* wlo = wtlo + (size_t)(half ? 128 : 0) * DH;
    float* outp = half ? outB : outA;
    const int n0 = (bb - half * nrb) * 128;

    if (t < 128) b2s[t] = mode ? b2prev[t] : 0.0f;
    #pragma unroll
    for (int i = 0; i < 4; ++i) {
        int cid = i * 256 + t;
        int cc = cid >> 4, ch = cid & 15;
        int sc = ch ^ (cc & 15);
        uint4 vh = *(const uint4*)(whi + (size_t)cc * DH + sc * 8);
        uint4 vl = *(const uint4*)(wlo + (size_t)cc * DH + sc * 8);
        *(uint4*)(smem + cid * 16) = vh;
        *(uint4*)(smem + 16384 + cid * 16) = vl;
    }
    __syncthreads();

    bf16x8 ahi[2][4], alo[2][4];
    #pragma unroll
    for (int rt = 0; rt < 2; ++rt) {
        int row = n0 + w * 32 + rt * 16 + (l & 15);
        if (row >= N) row = N - 1;
        size_t base = (size_t)row * DH + 8 * (l >> 4);
        const int kbase = 8 * (l >> 4);
        #pragma unroll
        for (int ks = 0; ks < 4; ++ks) {
            float v0, v1, v2, v3, v4, v5, v6, v7;
            if (mode == 0) {
                float4 a0 = *(const float4*)(zin + base + ks * 32);
                float4 a1 = *(const float4*)(zin + base + ks * 32 + 4);
                v0 = a0.x; v1 = a0.y; v2 = a0.z; v3 = a0.w;
                v4 = a1.x; v5 = a1.y; v6 = a1.z; v7 = a1.w;
            } else {
                uint4 u0 = *(const uint4*)(aggin + base + ks * 32);
                uint4 u1 = *(const uint4*)(aggin + base + ks * 32 + 4);
                float4 c0 = *(const float4*)&b2s[kbase + ks * 32];
                float4 c1 = *(const float4*)&b2s[kbase + ks * 32 + 4];
                v0 = fmaxf((u0.x == ENC_NEG_INF) ? 0.0f : dec_f(u0.x) + c0.x, 0.0f);
                v1 = fmaxf((u0.y == ENC_NEG_INF) ? 0.0f : dec_f(u0.y) + c0.y, 0.0f);
                v2 = fmaxf((u0.z == ENC_NEG_INF) ? 0.0f : dec_f(u0.z) + c0.z, 0.0f);
                v3 = fmaxf((u0.w == ENC_NEG_INF) ? 0.0f : dec_f(u0.w) + c0.w, 0.0f);
                v4 = fmaxf((u1.x == ENC_NEG_INF) ? 0.0f : dec_f(u1.x) + c1.x, 0.0f);
                v5 = fmaxf((u1.y == ENC_NEG_INF) ? 0.0f : dec_f(u1.y) + c1.y, 0.0f);
                v6 = fmaxf((u1.z == ENC_NEG_INF) ? 0.0f : dec_f(u1.z) + c1.z, 0.0f);
                v7 = fmaxf((u1.w == ENC_NEG_INF) ? 0.0f : dec_f(u1.w) + c1.w, 0.0f);
            }
            unsigned h01 = cvtpk(v0, v1), h23 = cvtpk(v2, v3);
            unsigned h45 = cvtpk(v4, v5), h67 = cvtpk(v6, v7);
            float l0 = v0 - __uint_as_float(h01 << 16);
            float l1 = v1 - __uint_as_float(h01 & 0xffff0000u);
            float l2 = v2 - __uint_as_float(h23 << 16);
            float l3 = v3 - __uint_as_float(h23 & 0xffff0000u);
            float l4 = v4 - __uint_as_float(h45 << 16);
            float l5 = v5 - __uint_as_float(h45 & 0xffff0000u);
            float l6 = v6 - __uint_as_float(h67 << 16);
            float l7 = v7 - __uint_as_float(h67 & 0xffff0000u);
            unsigned q01 = cvtpk(l0, l1), q23 = cvtpk(l2, l3);
            unsigned q45 = cvtpk(l4, l5), q67 = cvtpk(l6, l7);
            uint4 hp = {h01, h23, h45, h67};
            uint4 lp = {q01, q23, q45, q67};
            ahi[rt][ks] = *(bf16x8*)&hp;
            alo[rt][ks] = *(bf16x8*)&lp;
        }
    }
    f32x4 acc[2][8];
    #pragma unroll
    for (int rt = 0; rt < 2; ++rt)
        #pragma unroll
        for (int ct = 0; ct < 8; ++ct) acc[rt][ct] = (f32x4){0.f, 0.f, 0.f, 0.f};
    #pragma unroll
    for (int ct = 0; ct < 4; ++ct) {
        int colv = ct * 16 + (l & 15);
        #pragma unroll
        for (int ks = 0; ks < 4; ++ks) {
            int chb = ks * 4 + (l >> 4);
            int addr = colv * 256 + ((chb ^ (colv & 15)) << 4);
            bf16x8 bh = *(const bf16x8*)(smem + addr);
            bf16x8 bl = *(const bf16x8*)(smem + 16384 + addr);
            #pragma unroll
            for (int rt = 0; rt < 2; ++rt) {
                acc[rt][ct] = __builtin_amdgcn_mfma_f32_16x16x32_bf16(ahi[rt][ks], bh, acc[rt][ct], 0, 0, 0);
                acc[rt][ct] = __builtin_amdgcn_mfma_f32_16x16x32_bf16(ahi[rt][ks], bl, acc[rt][ct], 0, 0, 0);
                acc[rt][ct] = __builtin_amdgcn_mfma_f32_16x16x32_bf16(alo[rt][ks], bh, acc[rt][ct], 0, 0, 0);
            }
        }
    }
    __syncthreads();
    #pragma unroll
    for (int i = 0; i < 4; ++i) {
        int cid = i * 256 + t;
        int cc = cid >> 4, ch = cid & 15;
        int sc = ch ^ (cc & 15);
        uint4 vh = *(const uint4*)(whi + (size_t)(64 + cc) * DH + sc * 8);
        uint4 vl = *(const uint4*)(wlo + (size_t)(64 + cc) * DH + sc * 8);
        *(uint4*)(smem + cid * 16) = vh;
        *(uint4*)(smem + 16384 + cid * 16) = vl;
    }
    __syncthreads();
    #pragma unroll
    for (int ct = 4; ct < 8; ++ct) {
        int colv = ct * 16 + (l & 15);
        #pragma unroll
        for (int ks = 0; ks < 4; ++ks) {
            int chb = ks * 4 + (l >> 4);
            int addr = (colv & 63) * 256 + ((chb ^ (colv & 15)) << 4);
            bf16x8 bh = *(const bf16x8*)(smem + addr);
            bf16x8 bl = *(const bf16x8*)(smem + 16384 + addr);
            #pragma unroll
            for (int rt = 0; rt < 2; ++rt) {
                acc[rt][ct] = __builtin_amdgcn_mfma_f32_16x16x32_bf16(ahi[rt][ks], bh, acc[rt][ct], 0, 0, 0);
                acc[rt][ct] = __builtin_amdgcn_mfma_f32_16x16x32_bf16(ahi[rt][ks], bl, acc[rt][ct], 0, 0, 0);
                acc[rt][ct] = __builtin_amdgcn_mfma_f32_16x16x32_bf16(alo[rt][ks], bh, acc[rt][ct], 0, 0, 0);
            }
        }
    }
    #pragma unroll
    for (int ct = 0; ct < 8; ++ct) {
        int col = ct * 16 + (l & 15);
        float bv = half ? 0.0f : b1[col];
        #pragma unroll
        for (int rt = 0; rt < 2; ++rt)
            #pragma unroll
            for (int i = 0; i < 4; ++i) {
                int row = n0 + w * 32 + rt * 16 + (l >> 4) * 4 + i;
                if (row < N) outp[(size_t)row * DH + col] = acc[rt][ct][i] + bv;
            }
    }
}

// Edge kernel v9: 128 sorted edges x 128 cols, 512 thr / 8 waves.
// Col-split: waves 0-3 -> cols 0-63, waves 4-7 -> cols 64-127 (all edges each).
// Full W (hi+lo, 64KB) resident: no paging, 3 barriers total.
// Epilogue: per-wave-private 32x64 slab overlaid on W; serial run-max + few atomics.
__global__ __launch_bounds__(512, 4) void edge_mlp(
    const float* __restrict__ Afp, const float* __restrict__ Bfp,
    const int* __restrict__ src, const int* __restrict__ dst,
    const ushort_t* __restrict__ w2hi, const ushort_t* __restrict__ w2lo,
    unsigned* __restrict__ agg, int E) {
    __shared__ char smem[66048];     // W hi 32K | W lo 32K | sdst 512B; slabs overlay W
    int* sdst = (int*)(smem + 65536);
    const int t = threadIdx.x;
    const int w = t >> 6, l = t & 63;
    const int e0 = blockIdx.x * 128;
    const int ew = (w & 3) * 32;         // wave's edge sub-range
    const int colbase = (w >> 2) * 64;   // wave's column half

    if (t < 128) sdst[t] = dst[e0 + t];
    // stage full W (hi+lo), 16B-chunk XOR swizzle: 2048 chunks each
    #pragma unroll
    for (int i = 0; i < 4; ++i) {
        int cid = i * 512 + t;           // 0..2047
        int cc = cid >> 4, ch = cid & 15;
        int sc = ch ^ (cc & 15);
        uint4 vh = *(const uint4*)(w2hi + (size_t)cc * DH + sc * 8);
        uint4 vl = *(const uint4*)(w2lo + (size_t)cc * DH + sc * 8);
        *(uint4*)(smem + cid * 16) = vh;
        *(uint4*)(smem + 32768 + cid * 16) = vl;
    }

    // gather + relu + split (cvt_pk) into A-fragments (this wave's 32 edges)
    bf16x8 ahi[2][4], alo[2][4];
    #pragma unroll
    for (int rt = 0; rt < 2; ++rt) {
        int er = ew + rt * 16 + (l & 15);
        int dn = dst[e0 + er], sn = src[e0 + er];
        const float* pa = Afp + (size_t)dn * DH + 8 * (l >> 4);
        const float* pb = Bfp + (size_t)sn * DH + 8 * (l >> 4);
        #pragma unroll
        for (int ks = 0; ks < 4; ++ks) {
            float4 a0 = *(const float4*)(pa + ks * 32);
            float4 a1 = *(const float4*)(pa + ks * 32 + 4);
            float4 b0 = *(const float4*)(pb + ks * 32);
            float4 b1 = *(const float4*)(pb + ks * 32 + 4);
            float v0 = fmaxf(a0.x + b0.x, 0.f), v1 = fmaxf(a0.y + b0.y, 0.f);
            float v2 = fmaxf(a0.z + b0.z, 0.f), v3 = fmaxf(a0.w + b0.w, 0.f);
            float v4 = fmaxf(a1.x + b1.x, 0.f), v5 = fmaxf(a1.y + b1.y, 0.f);
            float v6 = fmaxf(a1.z + b1.z, 0.f), v7 = fmaxf(a1.w + b1.w, 0.f);
            unsigned h01 = cvtpk(v0, v1), h23 = cvtpk(v2, v3);
            unsigned h45 = cvtpk(v4, v5), h67 = cvtpk(v6, v7);
            float l0 = v0 - __uint_as_float(h01 << 16);
            float l1 = v1 - __uint_as_float(h01 & 0xffff0000u);
            float l2 = v2 - __uint_as_float(h23 << 16);
            float l3 = v3 - __uint_as_float(h23 & 0xffff0000u);
            float l4 = v4 - __uint_as_float(h45 << 16);
            float l5 = v5 - __uint_as_float(h45 & 0xffff0000u);
            float l6 = v6 - __uint_as_float(h67 << 16);
            float l7 = v7 - __uint_as_float(h67 & 0xffff0000u);
            unsigned q01 = cvtpk(l0, l1), q23 = cvtpk(l2, l3);
            unsigned q45 = cvtpk(l4, l5), q67 = cvtpk(l6, l7);
            uint4 hp = {h01, h23, h45, h67};
            uint4 lp = {q01, q23, q45, q67};
            ahi[rt][ks] = *(bf16x8*)&hp;
            alo[rt][ks] = *(bf16x8*)&lp;
        }
    }
    f32x4 acc[2][4];
    #pragma unroll
    for (int rt = 0; rt < 2; ++rt)
        #pragma unroll
        for (int ct = 0; ct < 4; ++ct) acc[rt][ct] = (f32x4){0.f, 0.f, 0.f, 0.f};
    __syncthreads();   // W + sdst visible
    #pragma unroll
    for (int ct = 0; ct < 4; ++ct) {
        int colv = colbase + ct * 16 + (l & 15);
        #pragma unroll
        for (int ks = 0; ks < 4; ++ks) {
            int chb = ks * 4 + (l >> 4);
            int addr = colv * 256 + ((chb ^ (colv & 15)) << 4);
            bf16x8 bh = *(const bf16x8*)(smem + addr);
            bf16x8 bl = *(const bf16x8*)(smem + 32768 + addr);
            #pragma unroll
            for (int rt = 0; rt < 2; ++rt) {
                acc[rt][ct] = __builtin_amdgcn_mfma_f32_16x16x32_bf16(ahi[rt][ks], bh, acc[rt][ct], 0, 0, 0);
                acc[rt][ct] = __builtin_amdgcn_mfma_f32_16x16x32_bf16(ahi[rt][ks], bl, acc[rt][ct], 0, 0, 0);
                acc[rt][ct] = __builtin_amdgcn_mfma_f32_16x16x32_bf16(alo[rt][ks], bh, acc[rt][ct], 0, 0, 0);
            }
        }
    }
    __syncthreads();   // all waves done reading W -> slabs may overlay
    // write per-wave 32x64 slab (swizzled, proven conflict-free pattern)
    float* slab = (float*)(smem + w * 8192);
    #pragma unroll
    for (int rt = 0; rt < 2; ++rt)
        #pragma unroll
        for (int ct = 0; ct < 4; ++ct) {
            int col64 = ct * 16 + (l & 15);
            #pragma unroll
            for (int i = 0; i < 4; ++i) {
                int row = rt * 16 + (l >> 4) * 4 + i;
                slab[row * 64 + (col64 ^ (((row >> 2) & 3) << 4))] = acc[rt][ct][i];
            }
        }
    __syncthreads();   // slab visible across lanes of the wave (and block)
    // per-wave serial run-max over 32 sorted rows; lane l owns column l
    const int col = l;
    float run = slab[(col ^ 0)];
    int cur = sdst[ew];
    #pragma unroll
    for (int rr = 1; rr < 32; ++rr) {
        float x = slab[rr * 64 + (col ^ (((rr >> 2) & 3) << 4))];
        int dd = sdst[ew + rr];
        if (dd != cur) {
            atomicMax(&agg[(size_t)cur * DH + colbase + col], enc_f(run));
            cur = dd; run = x;
        } else {
            run = fmaxf(run, x);
        }
    }
    atomicMax(&agg[(size_t)cur * DH + colbase + col], enc_f(run));
}

// final-layer output: out = (agg empty ? 0 : dec(agg) + b2[col]) fp32, no relu
__global__ void finalize_kernel(const unsigned* __restrict__ agg, const float* __restrict__ b2,
                                float* __restrict__ outf, int n) {
    int i = blockIdx.x * blockDim.x + threadIdx.x;
    int stride = gridDim.x * blockDim.x;
    for (; i < n; i += stride) {
        unsigned uv = agg[i];
        outf[i] = (uv == ENC_NEG_INF) ? 0.0f : dec_f(uv) + b2[i & (DH - 1)];
    }
}

extern "C" void kernel_launch(void* const* d_in, const int* in_sizes, int n_in,
                              void* d_out, int out_size, void* d_ws, size_t ws_size,
                              hipStream_t stream) {
    const float* z  = (const float*)d_in[0];
    const int*   ei = (const int*)d_in[1];
    const float* W1 = (const float*)d_in[2];
    const float* b1 = (const float*)d_in[3];
    const float* W2 = (const float*)d_in[4];
    const float* b2 = (const float*)d_in[5];
    const int N = 50000, D = DH, E = 800000;
    const int* srcp = ei;
    const int* dstp = ei + E;

    float* Abuf = (float*)d_ws;
    float* Bbuf = Abuf + (size_t)N * D;
    unsigned* agg = (unsigned*)(Bbuf + (size_t)N * D);
    ushort_t* W1t_hi = (ushort_t*)(agg + (size_t)N * D);
    ushort_t* W1t_lo = W1t_hi + NLAYER * 256 * D;
    ushort_t* W2t_hi = W1t_lo + NLAYER * 256 * D;
    ushort_t* W2t_lo = W2t_hi + NLAYER * D * D;
    unsigned* cnt = (unsigned*)(W2t_lo + NLAYER * D * D);
    unsigned* off = cnt + N;
    unsigned* bsum = off + N;
    int* s_src = (int*)(bsum + 64);
    int* s_dst = s_src + E;
    float* outp = (float*)d_out;

    convert_w<<<128, 256, 0, stream>>>(W1, W2, W1t_hi, W1t_lo, W2t_hi, W2t_lo);

    const int NB = (N + 1023) / 1024;   // 49
    fill_u<<<256, 256, 0, stream>>>(cnt, N, 0u);
    hist_kernel<<<1024, 256, 0, stream>>>(dstp, cnt, E);
    scan_local<<<NB, 1024, 0, stream>>>(cnt, off, bsum, N);
    scan_base<<<1, 64, 0, stream>>>(bsum, NB);
    scan_add<<<256, 256, 0, stream>>>(off, bsum, cnt, N);
    scatter_kernel<<<1024, 256, 0, stream>>>(srcp, dstp, off, cnt, s_src, s_dst, E);

    const int nrb = (N + 127) / 128;
    for (int l = 0; l < NLAYER; ++l) {
        node_gemm<<<2 * nrb, 256, 0, stream>>>(z, agg,
                                               (l > 0) ? (b2 + (size_t)(l - 1) * D) : nullptr,
                                               W1t_hi + ((size_t)l * 256) * D,
                                               W1t_lo + ((size_t)l * 256) * D,
                                               b1 + (size_t)l * D, Abuf, Bbuf,
                                               N, nrb, (l > 0) ? 1 : 0);
        fill_u<<<2048, 256, 0, stream>>>(agg, N * D, ENC_NEG_INF);
        edge_mlp<<<E / 128, 512, 0, stream>>>(Abuf, Bbuf, s_src, s_dst,
                                              W2t_hi + (size_t)l * D * D,
                                              W2t_lo + (size_t)l * D * D, agg, E);
    }
    finalize_kernel<<<2048, 256, 0, stream>>>(agg, b2 + (size_t)2 * D, outp, N * D);
}